// Round 2
// baseline (2251.034 us; speedup 1.0000x reference)
//
#include <hip/hip_runtime.h>

#define BATCH 4096

// ---- par sub-offsets (floats) ----
#define P_SWM   0
#define P_SWME  304
#define P_WP    608
#define P_WPE   969
#define P_GL    1330
#define P_GLVL  1349
#define P_CMT   1368
#define P_SC2   1392
#define P_SH2   1424
#define P_SC4   1456
#define P_SH4   1584
// par total 1712, reserve 2048

// ---- workspace layout (float offsets) ----
#define OFF_PAR 0L
#define OFF_W2R 2048L      // [ci16][tap9][co32]  = 4608
#define OFF_W3R 6656L      // [ci32][tap25][co64] = 51200
#define OFF_W4R 57856L     // [ci64][tap25][co128]= 204800
#define OFF_DYN 262656L    // then: wnum[chunk*608], wden[chunk*608], h2[chunk*6272]

__device__ __forceinline__ float sigmoidf_(float x) {
    return 1.0f / (1.0f + __expf(-x));
}
__device__ __forceinline__ float softplusf_(float x) { return log1pf(__expf(x)); }

// ---------------- prep: derived LTC params + BN folds + weight reorder ----------------
__global__ __launch_bounds__(256) void k_prep(
    const float* __restrict__ w2, const float* __restrict__ w3, const float* __restrict__ w4,
    const float* __restrict__ sw, const float* __restrict__ serev, const float* __restrict__ smask,
    const float* __restrict__ w,  const float* __restrict__ erev,  const float* __restrict__ mask,
    const float* __restrict__ gleak, const float* __restrict__ vleak, const float* __restrict__ cm,
    const float* __restrict__ b2, const float* __restrict__ g2, const float* __restrict__ be2,
    const float* __restrict__ m2, const float* __restrict__ v2,
    const float* __restrict__ b4, const float* __restrict__ g4, const float* __restrict__ be4,
    const float* __restrict__ m4, const float* __restrict__ v4,
    float* __restrict__ ws) {
    int gid = blockIdx.x * 256 + threadIdx.x, stride = gridDim.x * 256;
    float* w2r = ws + OFF_W2R;
    float* w3r = ws + OFF_W3R;
    float* w4r = ws + OFF_W4R;
    for (int i = gid; i < 4608; i += stride) {
        int co = i & 31, r = i >> 5, ci = r / 9, t = r % 9;
        w2r[i] = w2[(co * 16 + ci) * 9 + t];
    }
    for (int i = gid; i < 51200; i += stride) {
        int co = i & 63, r = i >> 6, ci = r / 25, t = r % 25;
        w3r[i] = w3[(co * 32 + ci) * 25 + t];
    }
    for (int i = gid; i < 204800; i += stride) {
        int co = i & 127, r = i >> 7, ci = r / 25, t = r % 25;
        w4r[i] = w4[(co * 64 + ci) * 25 + t];
    }
    if (blockIdx.x == 0) {
        float* par = ws + OFF_PAR;
        int tid = threadIdx.x;
        for (int i = tid; i < 304; i += 256) {
            float v_ = softplusf_(sw[i]) * smask[i];
            par[P_SWM + i] = v_;
            par[P_SWME + i] = v_ * serev[i];
        }
        for (int i = tid; i < 361; i += 256) {
            float v_ = softplusf_(w[i]) * mask[i];
            par[P_WP + i] = v_;
            par[P_WPE + i] = v_ * erev[i];
        }
        for (int i = tid; i < 19; i += 256) {
            float g = softplusf_(gleak[i]);
            par[P_GL + i] = g;
            par[P_GLVL + i] = g * vleak[i];
            par[P_CMT + i] = softplusf_(cm[i]) * 6.0f;   // cm / (1.0/ODE_UNFOLDS)
        }
        for (int i = tid; i < 32; i += 256) {
            float inv = g2[i] * __frsqrt_rn(v2[i] + 1e-5f);
            par[P_SC2 + i] = inv;
            par[P_SH2 + i] = (b2[i] - m2[i]) * inv + be2[i];   // (s+b2)*inv + (be2-m2*inv)
        }
        for (int i = tid; i < 128; i += 256) {
            float inv = g4[i] * __frsqrt_rn(v4[i] + 1e-5f);
            par[P_SC4 + i] = inv;
            par[P_SH4 + i] = (b4[i] - m4[i]) * inv + be4[i];
        }
    }
}

// ---------------- conv1 + ReLU + conv2 + BN + ReLU (one block per image) ----------------
__global__ __launch_bounds__(256) void k_conv12(
    const float* __restrict__ x, const float* __restrict__ w1, const float* __restrict__ b1,
    const float* __restrict__ ws, float* __restrict__ h2g) {
    __shared__ float xs[784];      // 28x28
    __shared__ float h1p[14400];   // 16 x 30 x 30 (pad 2 each side), zero borders
    const float* w2r = ws + OFF_W2R;
    const float* par = ws + OFF_PAR;
    int b = blockIdx.x, tid = threadIdx.x;
    for (int i = tid; i < 784; i += 256) xs[i] = x[(long)b * 784 + i];
    for (int i = tid; i < 14400; i += 256) h1p[i] = 0.f;
    __syncthreads();
    // conv1: 3x3 s1 p0 -> 16x26x26; thread: co = tid>>4 fixed, weights in regs
    {
        int co = tid >> 4, slot = tid & 15;
        float wr[9];
        #pragma unroll
        for (int i = 0; i < 9; i++) wr[i] = w1[co * 9 + i];
        float bb = b1[co];
        for (int k = 0; k < 43; k++) {
            int px = slot + (k << 4);
            if (px >= 676) break;
            int oh = px / 26, ow = px % 26;
            float s = bb;
            #pragma unroll
            for (int kh = 0; kh < 3; kh++)
                #pragma unroll
                for (int kw = 0; kw < 3; kw++)
                    s = fmaf(xs[(oh + kh) * 28 + ow + kw], wr[kh * 3 + kw], s);
            h1p[co * 900 + (oh + 2) * 30 + (ow + 2)] = fmaxf(s, 0.f);
        }
    }
    __syncthreads();
    // conv2: 3x3 s2 p2 -> 32x14x14, BN+ReLU; wave owns 8 co, lanes = pixels,
    // weights via wave-uniform index (s_load) from reordered w2r
    {
        int wv = __builtin_amdgcn_readfirstlane(tid >> 6);
        int lane = tid & 63;
        for (int seg = 0; seg < 4; seg++) {
            int px = seg * 64 + lane;
            bool actv = px < 196;
            int pxc = actv ? px : 195;
            int oh = pxc / 14, ow = pxc % 14;
            int pxbase = (oh * 2) * 30 + ow * 2;   // padded coords: row = oh*2+kh, col = ow*2+kw
            float acc[8];
            #pragma unroll
            for (int j = 0; j < 8; j++) acc[j] = 0.f;
            for (int ci = 0; ci < 16; ci++) {
                #pragma unroll
                for (int t = 0; t < 9; t++) {
                    int kh = t / 3, kw = t % 3;
                    float a = h1p[ci * 900 + pxbase + kh * 30 + kw];
                    const float* wp = w2r + (ci * 9 + t) * 32 + wv * 8;
                    #pragma unroll
                    for (int j = 0; j < 8; j++) acc[j] = fmaf(a, wp[j], acc[j]);
                }
            }
            if (actv) {
                #pragma unroll
                for (int j = 0; j < 8; j++) {
                    int co = wv * 8 + j;
                    float y = fmaf(acc[j], par[P_SC2 + co], par[P_SH2 + co]);
                    h2g[(long)b * 6272 + co * 196 + px] = fmaxf(y, 0.f);
                }
            }
        }
    }
}

// ---- conv3+ReLU, conv4+BN+ReLU, 2x2 maxpool, xin affine, sensory synapses ----
__global__ __launch_bounds__(256) void k_conv34s(
    const float* __restrict__ h2g, const float* __restrict__ b3g,
    const float* __restrict__ inw, const float* __restrict__ inb,
    const float* __restrict__ smu, const float* __restrict__ ssig,
    const float* __restrict__ ws,
    float* __restrict__ wn, float* __restrict__ wd) {
    __shared__ float h2s[6272];    // 32x14x14
    __shared__ float h3p[7744];    // 64 x 11 x 11 (pad 2), zero borders
    __shared__ float xin_s[512];   // [t=32][f=16]
    const float* w3r = ws + OFF_W3R;
    const float* w4r = ws + OFF_W4R;
    const float* par = ws + OFF_PAR;
    int b = blockIdx.x, tid = threadIdx.x;
    for (int i = tid; i < 6272; i += 256) h2s[i] = h2g[(long)b * 6272 + i];
    for (int i = tid; i < 7744; i += 256) h3p[i] = 0.f;
    __syncthreads();
    int wv = __builtin_amdgcn_readfirstlane(tid >> 6);
    int lane = tid & 63;
    // conv3: 5x5 s2 p2 -> 64x7x7; wave owns 16 co, lanes = 49 px, s_load weights
    {
        bool actv = lane < 49;
        int px = actv ? lane : 48;
        int oh = px / 7, ow = px % 7;
        float acc[16];
        #pragma unroll
        for (int j = 0; j < 16; j++) acc[j] = b3g[wv * 16 + j];
        for (int ci = 0; ci < 32; ci++) {
            #pragma unroll
            for (int kh = 0; kh < 5; kh++) {
                int ih = oh * 2 - 2 + kh;
                bool rok = (unsigned)ih < 14u;
                #pragma unroll
                for (int kw = 0; kw < 5; kw++) {
                    int iw = ow * 2 - 2 + kw;
                    bool ok = rok && ((unsigned)iw < 14u);
                    int idx = ok ? (ci * 196 + ih * 14 + iw) : 0;
                    float a = h2s[idx];
                    a = ok ? a : 0.f;
                    const float* wp = w3r + (ci * 25 + kh * 5 + kw) * 64 + wv * 16;
                    #pragma unroll
                    for (int j = 0; j < 16; j++) acc[j] = fmaf(a, wp[j], acc[j]);
                }
            }
        }
        if (actv) {
            #pragma unroll
            for (int j = 0; j < 16; j++)
                h3p[(wv * 16 + j) * 121 + (oh + 2) * 11 + (ow + 2)] = fmaxf(acc[j], 0.f);
        }
    }
    __syncthreads();
    // conv4: 5x5 s2 p2 -> 128x4x4, BN+ReLU, 2x2 maxpool, xin = seq*inw+inb
    // lane = px(16) x cc(4); wave covers co = wv*32 + cc*8 + j
    {
        int px = lane & 15, cc = lane >> 4;
        int oh = px >> 2, ow = px & 3;
        int pxbase = (oh * 2) * 11 + ow * 2;
        int cobase = wv * 32 + cc * 8;
        float acc[8];
        #pragma unroll
        for (int j = 0; j < 8; j++) acc[j] = 0.f;
        for (int ci = 0; ci < 64; ci++) {
            #pragma unroll
            for (int t = 0; t < 25; t++) {
                int kh = t / 5, kw = t % 5;
                float a = h3p[ci * 121 + pxbase + kh * 11 + kw];
                const float4* wq = (const float4*)(w4r + (long)(ci * 25 + t) * 128 + cobase);
                float4 wa = wq[0], wb = wq[1];
                acc[0] = fmaf(a, wa.x, acc[0]); acc[1] = fmaf(a, wa.y, acc[1]);
                acc[2] = fmaf(a, wa.z, acc[2]); acc[3] = fmaf(a, wa.w, acc[3]);
                acc[4] = fmaf(a, wb.x, acc[4]); acc[5] = fmaf(a, wb.y, acc[5]);
                acc[6] = fmaf(a, wb.z, acc[6]); acc[7] = fmaf(a, wb.w, acc[7]);
            }
        }
        int ph = px >> 3, pw = (px >> 1) & 1;
        #pragma unroll
        for (int j = 0; j < 8; j++) {
            int co = cobase + j;
            float y = fmaxf(fmaf(acc[j], par[P_SC4 + co], par[P_SH4 + co]), 0.f);
            // maxpool 2x2: px bit0 = ow lsb (xor 1), px bit2 = oh lsb (xor 4)
            y = fmaxf(y, __shfl_xor(y, 1));
            y = fmaxf(y, __shfl_xor(y, 4));
            if ((px & 5) == 0) {
                int ts = co >> 2;
                int f = ((co & 3) << 2) + (ph << 1) + pw;
                xin_s[ts * 16 + f] = fmaf(y, inw[f], inb[f]);
            }
        }
    }
    __syncthreads();
    // sensory synapses: wnum/wden [32 t][19 n]
    for (int idx = tid; idx < 608; idx += 256) {
        int tt = idx / 19, n = idx - tt * 19;
        float nu = 0.f, de = 0.f;
        #pragma unroll
        for (int s = 0; s < 16; s++) {
            float sg = sigmoidf_((xin_s[tt * 16 + s] - smu[s * 19 + n]) * ssig[s * 19 + n]);
            nu = fmaf(par[P_SWME + s * 19 + n], sg, nu);
            de = fmaf(par[P_SWM + s * 19 + n], sg, de);
        }
        wn[((long)b * 32 + tt) * 19 + n] = nu;
        wd[((long)b * 32 + tt) * 19 + n] = de;
    }
}

// ---------------- LTC recurrence: 3 images x 19 neurons per wave ----------------
__global__ __launch_bounds__(256) void k_ltc(
    const float* __restrict__ mu_g, const float* __restrict__ sg_g,
    const float* __restrict__ ws,
    const float* __restrict__ wn, const float* __restrict__ wd,
    const float* __restrict__ outw, const float* __restrict__ outb,
    float* __restrict__ out, int img0, int nimg) {
    const float* par = ws + OFF_PAR;
    int tid = threadIdx.x, wave = tid >> 6, lane = tid & 63;
    int li = lane / 19, j = lane - li * 19;
    if (li > 2) { li = 2; j = 18; }   // lanes 57..63 duplicate lane 56, no store
    int il = blockIdx.x * 12 + wave * 3 + li;   // chunk-local image
    int ilc = il < nimg ? il : nimg - 1;

    float muj[19], sgj[19], wpj[19], wpej[19];
    #pragma unroll
    for (int i = 0; i < 19; i++) {
        muj[i] = mu_g[i * 19 + j];
        sgj[i] = sg_g[i * 19 + j];
        wpj[i] = par[P_WP + i * 19 + j];
        wpej[i] = par[P_WPE + i * 19 + j];
    }
    float cmt = par[P_CMT + j], gl = par[P_GL + j], glvl = par[P_GLVL + j];
    float v = 0.f;
    for (int t = 0; t < 32; t++) {
        long base = ((long)ilc * 32 + t) * 19 + j;
        float wns = wn[base], wds = wd[base];
        #pragma unroll 1
        for (int u = 0; u < 6; u++) {
            float num = fmaf(cmt, v, glvl) + wns;
            float den = cmt + gl + wds;
            #pragma unroll
            for (int i = 0; i < 19; i++) {
                float vi = __shfl(v, li * 19 + i, 64);
                float sg = sigmoidf_((vi - muj[i]) * sgj[i]);
                num = fmaf(wpej[i], sg, num);
                den = fmaf(wpj[i], sg, den);
            }
            v = num / (den + 1e-8f);
        }
    }
    if (j < 2 && il < nimg && lane < 57)
        out[(long)(img0 + il) * 2 + j] = fmaf(v, outw[j], outb[j]);
}

extern "C" void kernel_launch(void* const* d_in, const int* in_sizes, int n_in,
                              void* d_out, int out_size, void* d_ws, size_t ws_size,
                              hipStream_t stream) {
    const float* x    = (const float*)d_in[0];
    const float* w1   = (const float*)d_in[1];
    const float* b1   = (const float*)d_in[2];
    const float* w2   = (const float*)d_in[3];
    const float* b2   = (const float*)d_in[4];
    const float* g2   = (const float*)d_in[5];
    const float* be2  = (const float*)d_in[6];
    const float* m2   = (const float*)d_in[7];
    const float* v2   = (const float*)d_in[8];
    const float* w3   = (const float*)d_in[9];
    const float* b3   = (const float*)d_in[10];
    const float* w4   = (const float*)d_in[11];
    const float* b4   = (const float*)d_in[12];
    const float* g4   = (const float*)d_in[13];
    const float* be4  = (const float*)d_in[14];
    const float* m4   = (const float*)d_in[15];
    const float* v4   = (const float*)d_in[16];
    const float* inw  = (const float*)d_in[17];
    const float* inb  = (const float*)d_in[18];
    const float* smu  = (const float*)d_in[19];
    const float* ssig = (const float*)d_in[20];
    const float* sw   = (const float*)d_in[21];
    const float* serv = (const float*)d_in[22];
    const float* smk  = (const float*)d_in[23];
    const float* mu_  = (const float*)d_in[24];
    const float* sig_ = (const float*)d_in[25];
    const float* w_   = (const float*)d_in[26];
    const float* erev = (const float*)d_in[27];
    const float* mask = (const float*)d_in[28];
    const float* glk  = (const float*)d_in[29];
    const float* vlk  = (const float*)d_in[30];
    const float* cm   = (const float*)d_in[31];
    const float* outw = (const float*)d_in[32];
    const float* outb = (const float*)d_in[33];
    float* ws = (float*)d_ws;

    k_prep<<<64, 256, 0, stream>>>(w2, w3, w4, sw, serv, smk, w_, erev, mask,
                                   glk, vlk, cm, b2, g2, be2, m2, v2,
                                   b4, g4, be4, m4, v4, ws);

    // auto-size batch chunk from ws_size: per-image = h2(6272) + wn/wd(1216) floats
    long avail = (long)(ws_size / 4) - OFF_DYN;
    long per = 6272 + 1216;
    int chunk = (int)(avail / per);
    if (chunk > BATCH) chunk = BATCH;
    if (chunk < 1) chunk = 1;

    float* wn  = ws + OFF_DYN;
    float* wdn = wn + (long)chunk * 608;
    float* h2  = wdn + (long)chunk * 608;

    for (int c0 = 0; c0 < BATCH; c0 += chunk) {
        int n = (BATCH - c0 < chunk) ? (BATCH - c0) : chunk;
        k_conv12<<<n, 256, 0, stream>>>(x + (long)c0 * 784, w1, b1, ws, h2);
        k_conv34s<<<n, 256, 0, stream>>>(h2, b3, inw, inb, smu, ssig, ws, wn, wdn);
        k_ltc<<<(n + 11) / 12, 256, 0, stream>>>(mu_, sig_, ws, wn, wdn, outw, outb,
                                                 (float*)d_out, c0, n);
    }
}

// Round 3
// 1644.731 us; speedup vs baseline: 1.3686x; 1.3686x over previous
//
#include <hip/hip_runtime.h>

#define BATCH 4096

// ---- par sub-offsets (floats) ----
#define P_SWM   0
#define P_SWME  304
#define P_WP    608
#define P_WPE   969
#define P_GL    1330
#define P_GLVL  1349
#define P_CMT   1368
#define P_SC2   1392
#define P_SH2   1424
#define P_SC4   1456
#define P_SH4   1584
// par total 1712, reserve 2048

// ---- workspace layout (float offsets) ----
#define OFF_PAR 0L
#define OFF_W2R 2048L      // [ci16][tap9][co32]  = 4608
#define OFF_W3R 6656L      // [ci32][tap25][co64] = 51200
#define OFF_W4R 57856L     // [ci64][tap25][co128]= 204800
#define OFF_DYN 262656L    // then: wnum[chunk*608], wden[chunk*608], h2[chunk*6272]

__device__ __forceinline__ float sigmoidf_(float x) {
    return 1.0f / (1.0f + __expf(-x));
}
__device__ __forceinline__ float softplusf_(float x) { return log1pf(__expf(x)); }

// ---------------- prep: derived LTC params + BN folds + weight reorder ----------------
__global__ __launch_bounds__(256) void k_prep(
    const float* __restrict__ w2, const float* __restrict__ w3, const float* __restrict__ w4,
    const float* __restrict__ sw, const float* __restrict__ serev, const float* __restrict__ smask,
    const float* __restrict__ w,  const float* __restrict__ erev,  const float* __restrict__ mask,
    const float* __restrict__ gleak, const float* __restrict__ vleak, const float* __restrict__ cm,
    const float* __restrict__ b2, const float* __restrict__ g2, const float* __restrict__ be2,
    const float* __restrict__ m2, const float* __restrict__ v2,
    const float* __restrict__ b4, const float* __restrict__ g4, const float* __restrict__ be4,
    const float* __restrict__ m4, const float* __restrict__ v4,
    float* __restrict__ ws) {
    int gid = blockIdx.x * 256 + threadIdx.x, stride = gridDim.x * 256;
    float* w2r = ws + OFF_W2R;
    float* w3r = ws + OFF_W3R;
    float* w4r = ws + OFF_W4R;
    for (int i = gid; i < 4608; i += stride) {
        int co = i & 31, r = i >> 5, ci = r / 9, t = r % 9;
        w2r[i] = w2[(co * 16 + ci) * 9 + t];
    }
    for (int i = gid; i < 51200; i += stride) {
        int co = i & 63, r = i >> 6, ci = r / 25, t = r % 25;
        w3r[i] = w3[(co * 32 + ci) * 25 + t];
    }
    for (int i = gid; i < 204800; i += stride) {
        int co = i & 127, r = i >> 7, ci = r / 25, t = r % 25;
        w4r[i] = w4[(co * 64 + ci) * 25 + t];
    }
    if (blockIdx.x == 0) {
        float* par = ws + OFF_PAR;
        int tid = threadIdx.x;
        for (int i = tid; i < 304; i += 256) {
            float v_ = softplusf_(sw[i]) * smask[i];
            par[P_SWM + i] = v_;
            par[P_SWME + i] = v_ * serev[i];
        }
        for (int i = tid; i < 361; i += 256) {
            float v_ = softplusf_(w[i]) * mask[i];
            par[P_WP + i] = v_;
            par[P_WPE + i] = v_ * erev[i];
        }
        for (int i = tid; i < 19; i += 256) {
            float g = softplusf_(gleak[i]);
            par[P_GL + i] = g;
            par[P_GLVL + i] = g * vleak[i];
            par[P_CMT + i] = softplusf_(cm[i]) * 6.0f;   // cm / (1.0/ODE_UNFOLDS)
        }
        for (int i = tid; i < 32; i += 256) {
            float inv = g2[i] * __frsqrt_rn(v2[i] + 1e-5f);
            par[P_SC2 + i] = inv;
            par[P_SH2 + i] = (b2[i] - m2[i]) * inv + be2[i];
        }
        for (int i = tid; i < 128; i += 256) {
            float inv = g4[i] * __frsqrt_rn(v4[i] + 1e-5f);
            par[P_SC4 + i] = inv;
            par[P_SH4 + i] = (b4[i] - m4[i]) * inv + be4[i];
        }
    }
}

// ---------------- conv1 + ReLU + conv2 + BN + ReLU (one block per image) ----------------
__global__ __launch_bounds__(256) void k_conv12(
    const float* __restrict__ x, const float* __restrict__ w1, const float* __restrict__ b1,
    const float* __restrict__ ws, float* __restrict__ h2g) {
    __shared__ float xs[784];      // 28x28
    __shared__ float h1p[14400];   // 16 x 30 x 30 (pad 2 each side), zero borders
    const float* w2r = ws + OFF_W2R;
    const float* par = ws + OFF_PAR;
    int b = blockIdx.x, tid = threadIdx.x;
    for (int i = tid; i < 784; i += 256) xs[i] = x[(long)b * 784 + i];
    for (int i = tid; i < 14400; i += 256) h1p[i] = 0.f;
    __syncthreads();
    // conv1: 3x3 s1 p0 -> 16x26x26; thread: co = tid>>4 fixed, weights in regs
    {
        int co = tid >> 4, slot = tid & 15;
        float wr[9];
        #pragma unroll
        for (int i = 0; i < 9; i++) wr[i] = w1[co * 9 + i];
        float bb = b1[co];
        for (int k = 0; k < 43; k++) {
            int px = slot + (k << 4);
            if (px >= 676) break;
            int oh = px / 26, ow = px % 26;
            float s = bb;
            #pragma unroll
            for (int kh = 0; kh < 3; kh++)
                #pragma unroll
                for (int kw = 0; kw < 3; kw++)
                    s = fmaf(xs[(oh + kh) * 28 + ow + kw], wr[kh * 3 + kw], s);
            h1p[co * 900 + (oh + 2) * 30 + (ow + 2)] = fmaxf(s, 0.f);
        }
    }
    __syncthreads();
    // conv2: 3x3 s2 p2 -> 32x14x14, BN+ReLU; wave owns 8 co, lanes = pixels
    {
        int wv = __builtin_amdgcn_readfirstlane(tid >> 6);
        int lane = tid & 63;
        for (int seg = 0; seg < 4; seg++) {
            int px = seg * 64 + lane;
            bool actv = px < 196;
            int pxc = actv ? px : 195;
            int oh = pxc / 14, ow = pxc % 14;
            int pxbase = (oh * 2) * 30 + ow * 2;
            float acc[8];
            #pragma unroll
            for (int j = 0; j < 8; j++) acc[j] = 0.f;
            for (int ci = 0; ci < 16; ci++) {
                #pragma unroll
                for (int t = 0; t < 9; t++) {
                    int kh = t / 3, kw = t % 3;
                    float a = h1p[ci * 900 + pxbase + kh * 30 + kw];
                    const float* wp = w2r + (ci * 9 + t) * 32 + wv * 8;
                    #pragma unroll
                    for (int j = 0; j < 8; j++) acc[j] = fmaf(a, wp[j], acc[j]);
                }
            }
            if (actv) {
                #pragma unroll
                for (int j = 0; j < 8; j++) {
                    int co = wv * 8 + j;
                    float y = fmaf(acc[j], par[P_SC2 + co], par[P_SH2 + co]);
                    h2g[(long)b * 6272 + co * 196 + px] = fmaxf(y, 0.f);
                }
            }
        }
    }
}

// ---- conv3+ReLU, conv4+BN+ReLU, 2x2 maxpool, xin affine, sensory synapses ----
// LDS: h2s 25088 B + h3p 22528 B = 47616 B -> 3 blocks/CU. xin overlays h2s.
__global__ __launch_bounds__(256, 3) void k_conv34s(
    const float* __restrict__ h2g, const float* __restrict__ b3g,
    const float* __restrict__ inw, const float* __restrict__ inb,
    const float* __restrict__ smu, const float* __restrict__ ssig,
    const float* __restrict__ ws,
    float* __restrict__ wn, float* __restrict__ wd) {
    __shared__ float h2s[6272];    // 32 x 14 x 14 (doubles as xin[32][16] later)
    __shared__ float h3p[5632];    // 64 x 11(rows -2..8) x 8(cols 0..6 + pad), zero pads
    const float* w3r = ws + OFF_W3R;
    const float* w4r = ws + OFF_W4R;
    const float* par = ws + OFF_PAR;
    int b = blockIdx.x, tid = threadIdx.x;
    {
        const float4* src = (const float4*)(h2g + (long)b * 6272);
        float4* dst = (float4*)h2s;
        for (int i = tid; i < 1568; i += 256) dst[i] = src[i];
        float4* hz = (float4*)h3p;
        float4 z; z.x = z.y = z.z = z.w = 0.f;
        for (int i = tid; i < 1408; i += 256) hz[i] = z;
    }
    __syncthreads();
    int wv = __builtin_amdgcn_readfirstlane(tid >> 6);
    int lane = tid & 63;
    // conv3: 5x5 s2 p2 -> 64x7x7; wave owns 16 co, lanes = 49 px, s_load weights
    {
        bool actv = lane < 49;
        int px = actv ? lane : 48;
        int oh = px / 7, ow = px % 7;
        float acc[16];
        #pragma unroll
        for (int j = 0; j < 16; j++) acc[j] = b3g[wv * 16 + j];
        for (int ci = 0; ci < 32; ci++) {
            #pragma unroll
            for (int kh = 0; kh < 5; kh++) {
                int ih = oh * 2 - 2 + kh;
                bool rok = (unsigned)ih < 14u;
                #pragma unroll
                for (int kw = 0; kw < 5; kw++) {
                    int iw = ow * 2 - 2 + kw;
                    bool ok = rok && ((unsigned)iw < 14u);
                    int idx = ok ? (ci * 196 + ih * 14 + iw) : 0;
                    float a = h2s[idx];
                    a = ok ? a : 0.f;
                    const float* wp = w3r + (ci * 25 + kh * 5 + kw) * 64 + wv * 16;
                    #pragma unroll
                    for (int j = 0; j < 16; j++) acc[j] = fmaf(a, wp[j], acc[j]);
                }
            }
        }
        if (actv) {
            #pragma unroll
            for (int j = 0; j < 16; j++)
                h3p[(wv * 16 + j) * 88 + (oh + 2) * 8 + ow] = fmaxf(acc[j], 0.f);
        }
    }
    __syncthreads();
    // conv4: 5x5 s2 p2 -> 128x4x4, BN+ReLU, in-register 2x2 maxpool, xin
    // lane = pxh(2) x co32; co = wv*32 + (lane&31); px = pxh*8 + p, p in [0,8)
    {
        int l31 = lane & 31, pxh = lane >> 5;
        int co = wv * 32 + l31;
        float acc[8];
        #pragma unroll
        for (int j = 0; j < 8; j++) acc[j] = 0.f;
        float wA[25], wB[25];
        const float* wbase = w4r + co;
        #pragma unroll
        for (int t = 0; t < 25; t++) wA[t] = wbase[t * 128];   // ci = 0
        float4 rwq[14];
        const float* rwf = (const float*)rwq;

        #define LDW(CI, WBUF) { const float* wp_ = wbase + (CI) * 3200; \
            _Pragma("unroll") for (int t = 0; t < 25; t++) WBUF[t] = wp_[t * 128]; }
        #define BODY(CI, WBUF) { \
            const float4* hq_ = (const float4*)h3p + 22 * (CI) + 8 * pxh; \
            _Pragma("unroll") for (int lr = 0; lr < 14; lr++) rwq[lr] = hq_[lr]; \
            _Pragma("unroll") for (int p = 0; p < 8; p++) { \
                const int ohq_ = p >> 2, ow_ = p & 3; \
                _Pragma("unroll") for (int kh = 0; kh < 5; kh++) { \
                    const int lr_ = 2 * ohq_ + kh; \
                    _Pragma("unroll") for (int kw = 0; kw < 5; kw++) { \
                        const int c_ = 2 * ow_ - 2 + kw; \
                        if (c_ >= 0 && c_ <= 6) \
                            acc[p] = fmaf(rwf[lr_ * 8 + c_], WBUF[kh * 5 + kw], acc[p]); \
                    } } } }

        for (int ci = 0; ci < 64; ci += 2) {
            LDW(ci + 1, wB);
            BODY(ci, wA);
            int cin = (ci + 2 < 64) ? ci + 2 : 63;
            LDW(cin, wA);
            BODY(ci + 1, wB);
        }
        #undef LDW
        #undef BODY
        // BN + ReLU per element, then 2x2 maxpool entirely in-register.
        float sc = par[P_SC4 + co], sh = par[P_SH4 + co];
        float y[8];
        #pragma unroll
        for (int p = 0; p < 8; p++) y[p] = fmaxf(fmaf(acc[p], sc, sh), 0.f);
        float pooled[2];
        #pragma unroll
        for (int q = 0; q < 2; q++)
            pooled[q] = fmaxf(fmaxf(y[2 * q], y[2 * q + 1]),
                              fmaxf(y[2 * q + 4], y[2 * q + 5]));
        __syncthreads();   // h2s dead; reuse as xin[32][16]
        float* xin_s = h2s;
        #pragma unroll
        for (int q = 0; q < 2; q++) {
            int ts = co >> 2;
            int f = ((co & 3) << 2) + (pxh << 1) + q;
            xin_s[ts * 16 + f] = fmaf(pooled[q], inw[f], inb[f]);
        }
    }
    __syncthreads();
    // sensory synapses: wnum/wden [32 t][19 n]
    const float* xin_s = h2s;
    for (int idx = tid; idx < 608; idx += 256) {
        int tt = idx / 19, n = idx - tt * 19;
        float nu = 0.f, de = 0.f;
        #pragma unroll
        for (int s = 0; s < 16; s++) {
            float sg = sigmoidf_((xin_s[tt * 16 + s] - smu[s * 19 + n]) * ssig[s * 19 + n]);
            nu = fmaf(par[P_SWME + s * 19 + n], sg, nu);
            de = fmaf(par[P_SWM + s * 19 + n], sg, de);
        }
        wn[((long)b * 32 + tt) * 19 + n] = nu;
        wd[((long)b * 32 + tt) * 19 + n] = de;
    }
}

// ---------------- LTC recurrence: 3 images x 19 neurons per wave ----------------
__global__ __launch_bounds__(256) void k_ltc(
    const float* __restrict__ mu_g, const float* __restrict__ sg_g,
    const float* __restrict__ ws,
    const float* __restrict__ wn, const float* __restrict__ wd,
    const float* __restrict__ outw, const float* __restrict__ outb,
    float* __restrict__ out, int img0, int nimg) {
    const float* par = ws + OFF_PAR;
    int tid = threadIdx.x, wave = tid >> 6, lane = tid & 63;
    int li = lane / 19, j = lane - li * 19;
    if (li > 2) { li = 2; j = 18; }   // lanes 57..63 duplicate lane 56, no store
    int il = blockIdx.x * 12 + wave * 3 + li;
    int ilc = il < nimg ? il : nimg - 1;

    float muj[19], sgj[19], wpj[19], wpej[19];
    #pragma unroll
    for (int i = 0; i < 19; i++) {
        muj[i] = mu_g[i * 19 + j];
        sgj[i] = sg_g[i * 19 + j];
        wpj[i] = par[P_WP + i * 19 + j];
        wpej[i] = par[P_WPE + i * 19 + j];
    }
    float cmt = par[P_CMT + j], gl = par[P_GL + j], glvl = par[P_GLVL + j];
    float v = 0.f;
    for (int t = 0; t < 32; t++) {
        long base = ((long)ilc * 32 + t) * 19 + j;
        float wns = wn[base], wds = wd[base];
        #pragma unroll 1
        for (int u = 0; u < 6; u++) {
            float num = fmaf(cmt, v, glvl) + wns;
            float den = cmt + gl + wds;
            #pragma unroll
            for (int i = 0; i < 19; i++) {
                float vi = __shfl(v, li * 19 + i, 64);
                float sg = sigmoidf_((vi - muj[i]) * sgj[i]);
                num = fmaf(wpej[i], sg, num);
                den = fmaf(wpj[i], sg, den);
            }
            v = num / (den + 1e-8f);
        }
    }
    if (j < 2 && il < nimg && lane < 57)
        out[(long)(img0 + il) * 2 + j] = fmaf(v, outw[j], outb[j]);
}

extern "C" void kernel_launch(void* const* d_in, const int* in_sizes, int n_in,
                              void* d_out, int out_size, void* d_ws, size_t ws_size,
                              hipStream_t stream) {
    const float* x    = (const float*)d_in[0];
    const float* w1   = (const float*)d_in[1];
    const float* b1   = (const float*)d_in[2];
    const float* w2   = (const float*)d_in[3];
    const float* b2   = (const float*)d_in[4];
    const float* g2   = (const float*)d_in[5];
    const float* be2  = (const float*)d_in[6];
    const float* m2   = (const float*)d_in[7];
    const float* v2   = (const float*)d_in[8];
    const float* w3   = (const float*)d_in[9];
    const float* b3   = (const float*)d_in[10];
    const float* w4   = (const float*)d_in[11];
    const float* b4   = (const float*)d_in[12];
    const float* g4   = (const float*)d_in[13];
    const float* be4  = (const float*)d_in[14];
    const float* m4   = (const float*)d_in[15];
    const float* v4   = (const float*)d_in[16];
    const float* inw  = (const float*)d_in[17];
    const float* inb  = (const float*)d_in[18];
    const float* smu  = (const float*)d_in[19];
    const float* ssig = (const float*)d_in[20];
    const float* sw   = (const float*)d_in[21];
    const float* serv = (const float*)d_in[22];
    const float* smk  = (const float*)d_in[23];
    const float* mu_  = (const float*)d_in[24];
    const float* sig_ = (const float*)d_in[25];
    const float* w_   = (const float*)d_in[26];
    const float* erev = (const float*)d_in[27];
    const float* mask = (const float*)d_in[28];
    const float* glk  = (const float*)d_in[29];
    const float* vlk  = (const float*)d_in[30];
    const float* cm   = (const float*)d_in[31];
    const float* outw = (const float*)d_in[32];
    const float* outb = (const float*)d_in[33];
    float* ws = (float*)d_ws;

    k_prep<<<64, 256, 0, stream>>>(w2, w3, w4, sw, serv, smk, w_, erev, mask,
                                   glk, vlk, cm, b2, g2, be2, m2, v2,
                                   b4, g4, be4, m4, v4, ws);

    // auto-size batch chunk from ws_size: per-image = h2(6272) + wn/wd(1216) floats
    long avail = (long)(ws_size / 4) - OFF_DYN;
    long per = 6272 + 1216;
    int chunk = (int)(avail / per);
    if (chunk > BATCH) chunk = BATCH;
    if (chunk < 1) chunk = 1;

    float* wn  = ws + OFF_DYN;
    float* wdn = wn + (long)chunk * 608;
    float* h2  = wdn + (long)chunk * 608;

    for (int c0 = 0; c0 < BATCH; c0 += chunk) {
        int n = (BATCH - c0 < chunk) ? (BATCH - c0) : chunk;
        k_conv12<<<n, 256, 0, stream>>>(x + (long)c0 * 784, w1, b1, ws, h2);
        k_conv34s<<<n, 256, 0, stream>>>(h2, b3, inw, inb, smu, ssig, ws, wn, wdn);
        k_ltc<<<(n + 11) / 12, 256, 0, stream>>>(mu_, sig_, ws, wn, wdn, outw, outb,
                                                 (float*)d_out, c0, n);
    }
}

// Round 4
// 899.127 us; speedup vs baseline: 2.5036x; 1.8293x over previous
//
#include <hip/hip_runtime.h>

#define BATCH 4096
typedef unsigned short u16_t;

// ---- par sub-offsets (floats) ----
#define P_SWM   0
#define P_SWME  304
#define P_WP    608
#define P_WPE   969
#define P_GL    1330
#define P_GLVL  1349
#define P_CMT   1368
#define P_SC2   1392
#define P_SH2   1424
#define P_SC4   1456
#define P_SH4   1584
// par total 1712, reserve 2048

// ---- workspace layout (float offsets) ----
#define OFF_PAR 0L
#define OFF_W2R 2048L      // [ci16][tap9][co32] = 4608 floats
#define OFF_B3F 6656L      // bf16 frag-ordered conv3 W: [pl2][nt2][s50][ln64][j8] = 102400 u16 = 51200 f
#define OFF_B4F 57856L     // bf16 frag-ordered conv4 W: [pl2][nt4][s100][ln64][j8] = 409600 u16 = 204800 f
#define OFF_DYN 262656L    // then per chunk: wnum[chunk*608], wden[chunk*608], h2[chunk*6272]

typedef __attribute__((ext_vector_type(8))) short short8;
typedef __attribute__((ext_vector_type(16))) float f32x16;
#define MFMA(a, b, c) __builtin_amdgcn_mfma_f32_32x32x16_bf16(a, b, c, 0, 0, 0)

union U8 { unsigned u[4]; short8 v; };

__device__ __forceinline__ float sigmoidf_(float x) {
    return 1.0f / (1.0f + __expf(-x));
}
__device__ __forceinline__ float softplusf_(float x) { return log1pf(__expf(x)); }

// split fp32 -> packed (hi trunc-bf16 in low16, lo rne-bf16 of residual in high16)
__device__ __forceinline__ unsigned splitpack(float f) {
    unsigned u = __float_as_uint(f);
    float rsd = f - __uint_as_float(u & 0xFFFF0000u);
    unsigned ur = __float_as_uint(rsd);
    ur = ur + 0x7FFFu + ((ur >> 16) & 1u);
    return (u >> 16) | (ur & 0xFFFF0000u);
}

// ---------------- prep: derived LTC params + BN folds + weight split/reorder ----------------
__global__ __launch_bounds__(256) void k_prep(
    const float* __restrict__ w2, const float* __restrict__ w3, const float* __restrict__ w4,
    const float* __restrict__ sw, const float* __restrict__ serev, const float* __restrict__ smask,
    const float* __restrict__ w,  const float* __restrict__ erev,  const float* __restrict__ mask,
    const float* __restrict__ gleak, const float* __restrict__ vleak, const float* __restrict__ cm,
    const float* __restrict__ b2, const float* __restrict__ g2, const float* __restrict__ be2,
    const float* __restrict__ m2, const float* __restrict__ v2,
    const float* __restrict__ b4, const float* __restrict__ g4, const float* __restrict__ be4,
    const float* __restrict__ m4, const float* __restrict__ v4,
    float* __restrict__ ws) {
    int gid = blockIdx.x * 256 + threadIdx.x, stride = gridDim.x * 256;
    float* w2r = ws + OFF_W2R;
    u16_t* b3f = (u16_t*)(ws + OFF_B3F);
    u16_t* b4f = (u16_t*)(ws + OFF_B4F);
    for (int i = gid; i < 4608; i += stride) {
        int co = i & 31, r = i >> 5, ci = r / 9, t = r % 9;
        w2r[i] = w2[(co * 16 + ci) * 9 + t];
    }
    // conv3 weights, frag order, k = tap*32 + ci
    for (int i = gid; i < 102400; i += stride) {
        int j = i & 7, ln = (i >> 3) & 63;
        int t = i >> 9;
        int s = t % 50, r = t / 50;
        int nt = r & 1, pl = r >> 1;
        int k = s * 16 + (ln >> 5) * 8 + j;
        int tap = k >> 5, ci = k & 31;
        int co = nt * 32 + (ln & 31);
        float v = w3[(co * 32 + ci) * 25 + tap];
        unsigned u = __float_as_uint(v);
        if (pl == 0) b3f[i] = (u16_t)(u >> 16);
        else {
            float rsd = v - __uint_as_float(u & 0xFFFF0000u);
            unsigned ur = __float_as_uint(rsd);
            ur = ur + 0x7FFFu + ((ur >> 16) & 1u);
            b3f[i] = (u16_t)(ur >> 16);
        }
    }
    // conv4 weights, frag order, k = tap*64 + ci
    for (int i = gid; i < 409600; i += stride) {
        int j = i & 7, ln = (i >> 3) & 63;
        int t = i >> 9;
        int s = t % 100, r = t / 100;
        int nt = r & 3, pl = r >> 2;
        int k = s * 16 + (ln >> 5) * 8 + j;
        int tap = k >> 6, ci = k & 63;
        int co = nt * 32 + (ln & 31);
        float v = w4[(co * 64 + ci) * 25 + tap];
        unsigned u = __float_as_uint(v);
        if (pl == 0) b4f[i] = (u16_t)(u >> 16);
        else {
            float rsd = v - __uint_as_float(u & 0xFFFF0000u);
            unsigned ur = __float_as_uint(rsd);
            ur = ur + 0x7FFFu + ((ur >> 16) & 1u);
            b4f[i] = (u16_t)(ur >> 16);
        }
    }
    if (blockIdx.x == 0) {
        float* par = ws + OFF_PAR;
        int tid = threadIdx.x;
        for (int i = tid; i < 304; i += 256) {
            float v_ = softplusf_(sw[i]) * smask[i];
            par[P_SWM + i] = v_;
            par[P_SWME + i] = v_ * serev[i];
        }
        for (int i = tid; i < 361; i += 256) {
            float v_ = softplusf_(w[i]) * mask[i];
            par[P_WP + i] = v_;
            par[P_WPE + i] = v_ * erev[i];
        }
        for (int i = tid; i < 19; i += 256) {
            float g = softplusf_(gleak[i]);
            par[P_GL + i] = g;
            par[P_GLVL + i] = g * vleak[i];
            par[P_CMT + i] = softplusf_(cm[i]) * 6.0f;
        }
        for (int i = tid; i < 32; i += 256) {
            float inv = g2[i] * __frsqrt_rn(v2[i] + 1e-5f);
            par[P_SC2 + i] = inv;
            par[P_SH2 + i] = (b2[i] - m2[i]) * inv + be2[i];
        }
        for (int i = tid; i < 128; i += 256) {
            float inv = g4[i] * __frsqrt_rn(v4[i] + 1e-5f);
            par[P_SC4 + i] = inv;
            par[P_SH4 + i] = (b4[i] - m4[i]) * inv + be4[i];
        }
    }
}

// ---------------- conv1 + ReLU + conv2 + BN + ReLU (one block per image) ----------------
__global__ __launch_bounds__(256) void k_conv12(
    const float* __restrict__ x, const float* __restrict__ w1, const float* __restrict__ b1,
    const float* __restrict__ ws, float* __restrict__ h2g) {
    __shared__ float xs[784];      // 28x28
    __shared__ float h1p[14400];   // 16 x 30 x 30 (pad 2 each side), zero borders
    const float* w2r = ws + OFF_W2R;
    const float* par = ws + OFF_PAR;
    int b = blockIdx.x, tid = threadIdx.x;
    for (int i = tid; i < 784; i += 256) xs[i] = x[(long)b * 784 + i];
    for (int i = tid; i < 14400; i += 256) h1p[i] = 0.f;
    __syncthreads();
    {
        int co = tid >> 4, slot = tid & 15;
        float wr[9];
        #pragma unroll
        for (int i = 0; i < 9; i++) wr[i] = w1[co * 9 + i];
        float bb = b1[co];
        for (int k = 0; k < 43; k++) {
            int px = slot + (k << 4);
            if (px >= 676) break;
            int oh = px / 26, ow = px % 26;
            float s = bb;
            #pragma unroll
            for (int kh = 0; kh < 3; kh++)
                #pragma unroll
                for (int kw = 0; kw < 3; kw++)
                    s = fmaf(xs[(oh + kh) * 28 + ow + kw], wr[kh * 3 + kw], s);
            h1p[co * 900 + (oh + 2) * 30 + (ow + 2)] = fmaxf(s, 0.f);
        }
    }
    __syncthreads();
    {
        int wv = __builtin_amdgcn_readfirstlane(tid >> 6);
        int lane = tid & 63;
        for (int seg = 0; seg < 4; seg++) {
            int px = seg * 64 + lane;
            bool actv = px < 196;
            int pxc = actv ? px : 195;
            int oh = pxc / 14, ow = pxc % 14;
            int pxbase = (oh * 2) * 30 + ow * 2;
            float acc[8];
            #pragma unroll
            for (int j = 0; j < 8; j++) acc[j] = 0.f;
            for (int ci = 0; ci < 16; ci++) {
                #pragma unroll
                for (int t = 0; t < 9; t++) {
                    int kh = t / 3, kw = t % 3;
                    float a = h1p[ci * 900 + pxbase + kh * 30 + kw];
                    const float* wp = w2r + (ci * 9 + t) * 32 + wv * 8;
                    #pragma unroll
                    for (int j = 0; j < 8; j++) acc[j] = fmaf(a, wp[j], acc[j]);
                }
            }
            if (actv) {
                #pragma unroll
                for (int j = 0; j < 8; j++) {
                    int co = wv * 8 + j;
                    float y = fmaf(acc[j], par[P_SC2 + co], par[P_SH2 + co]);
                    h2g[(long)b * 6272 + co * 196 + px] = fmaxf(y, 0.f);
                }
            }
        }
    }
}

// ---- conv3 + conv4 as bf16-split MFMA GEMMs + BN/ReLU/pool/xin + sensory ----
// LDS: h2s 25088 B (packed hi/lo) + h3s 12544 B = 37632 B -> up to 4 blocks/CU.
__global__ __launch_bounds__(256, 4) void k_conv34s(
    const float* __restrict__ h2g, const float* __restrict__ b3g,
    const float* __restrict__ inw, const float* __restrict__ inb,
    const float* __restrict__ smu, const float* __restrict__ ssig,
    const float* __restrict__ ws,
    float* __restrict__ wn, float* __restrict__ wd) {
    __shared__ unsigned h2s[6272];   // 32x14x14 packed (hi,lo); later reused as xin[32][16] f32
    __shared__ unsigned h3s[3136];   // 64x7x7 packed (hi,lo)
    const float* par = ws + OFF_PAR;
    int b = blockIdx.x, tid = threadIdx.x;
    // phase 0: load h2, split to bf16 hi/lo packed
    {
        const float* src = h2g + (long)b * 6272;
        for (int i = tid; i < 6272; i += 256) h2s[i] = splitpack(src[i]);
    }
    __syncthreads();
    int wv = tid >> 6;
    int lane = tid & 63;
    int mloc = lane & 31, hf = lane >> 5, half8 = hf * 8;

    // ---- conv3 GEMM: C[64px x 64co], K=800 (k = tap*32 + ci) ----
    {
        int mt = wv & 1, nt = wv >> 1;
        int px = mt * 32 + mloc;
        int oh = px / 7, ow = px % 7;
        bool pxok = px < 49;
        int oh2 = oh * 2 - 2, ow2 = ow * 2 - 2;
        int co3 = nt * 32 + mloc;
        float bias = b3g[co3];
        f32x16 acc;
        #pragma unroll
        for (int i = 0; i < 16; i++) acc[i] = bias;
        const u16_t* B3 = (const u16_t*)(ws + OFF_B3F);
        const short8* pbh = (const short8*)(B3 + (long)(nt * 50) * 512) + lane;
        const short8* pbl = (const short8*)(B3 + (long)((2 + nt) * 50) * 512) + lane;
        int s = 0;
        for (int kh = 0; kh < 5; kh++) {
            int ih = oh2 + kh;
            #pragma unroll
            for (int kw = 0; kw < 5; kw++) {
                int iw = ow2 + kw;
                bool ok = pxok && ((unsigned)ih < 14u) && ((unsigned)iw < 14u);
                int off = ih * 14 + iw;
                unsigned zm = ok ? 0xFFFFFFFFu : 0u;
                #pragma unroll
                for (int sub = 0; sub < 2; sub++) {
                    int base = ok ? ((sub * 16 + half8) * 196 + off) : 0;
                    unsigned w_[8];
                    #pragma unroll
                    for (int j = 0; j < 8; j++) w_[j] = h2s[base + j * 196];
                    U8 ah, al;
                    #pragma unroll
                    for (int d = 0; d < 4; d++) {
                        unsigned w0 = w_[2 * d] & zm, w1 = w_[2 * d + 1] & zm;
                        ah.u[d] = ((w1 & 0xFFFFu) << 16) | (w0 & 0xFFFFu);
                        al.u[d] = (w1 & 0xFFFF0000u) | (w0 >> 16);
                    }
                    short8 bh = pbh[s * 64];
                    short8 bl = pbl[s * 64];
                    acc = MFMA(ah.v, bh, acc);
                    acc = MFMA(ah.v, bl, acc);
                    acc = MFMA(al.v, bh, acc);
                    s++;
                }
            }
        }
        // epilogue: ReLU, split, write h3 packed [co][px]
        #pragma unroll
        for (int r5 = 0; r5 < 16; r5++) {
            int row = (r5 & 3) + 8 * (r5 >> 2) + 4 * hf;
            int pxw = mt * 32 + row;
            if (pxw < 49) {
                float y = fmaxf(acc[r5], 0.f);
                h3s[co3 * 49 + pxw] = splitpack(y);
            }
        }
    }
    __syncthreads();
    // ---- conv4 GEMM: C[32px(16 valid) x 128co], K=1600 (k = tap*64 + ci) ----
    {
        int oh = mloc >> 2, ow = mloc & 3;
        bool pxok = mloc < 16;
        int oh2 = oh * 2 - 2, ow2 = ow * 2 - 2;
        int co4 = wv * 32 + mloc;
        f32x16 acc;
        #pragma unroll
        for (int i = 0; i < 16; i++) acc[i] = 0.f;
        const u16_t* B4 = (const u16_t*)(ws + OFF_B4F);
        const short8* pbh = (const short8*)(B4 + (long)(wv * 100) * 512) + lane;
        const short8* pbl = (const short8*)(B4 + (long)((4 + wv) * 100) * 512) + lane;
        int s = 0;
        for (int kh = 0; kh < 5; kh++) {
            int ih = oh2 + kh;
            #pragma unroll
            for (int kw = 0; kw < 5; kw++) {
                int iw = ow2 + kw;
                bool ok = pxok && ((unsigned)ih < 7u) && ((unsigned)iw < 7u);
                int off = ih * 7 + iw;
                unsigned zm = ok ? 0xFFFFFFFFu : 0u;
                #pragma unroll
                for (int sub = 0; sub < 4; sub++) {
                    int base = ok ? ((sub * 16 + half8) * 49 + off) : 0;
                    unsigned w_[8];
                    #pragma unroll
                    for (int j = 0; j < 8; j++) w_[j] = h3s[base + j * 49];
                    U8 ah, al;
                    #pragma unroll
                    for (int d = 0; d < 4; d++) {
                        unsigned w0 = w_[2 * d] & zm, w1 = w_[2 * d + 1] & zm;
                        ah.u[d] = ((w1 & 0xFFFFu) << 16) | (w0 & 0xFFFFu);
                        al.u[d] = (w1 & 0xFFFF0000u) | (w0 >> 16);
                    }
                    short8 bh = pbh[s * 64];
                    short8 bl = pbl[s * 64];
                    acc = MFMA(ah.v, bh, acc);
                    acc = MFMA(ah.v, bl, acc);
                    acc = MFMA(al.v, bh, acc);
                    s++;
                }
            }
        }
        // epilogue: BN+ReLU (regs 0..7 hold px<16), in-reg+shfl 2x2 maxpool, xin
        float sc = par[P_SC4 + co4], sh = par[P_SH4 + co4];
        float y[8];
        #pragma unroll
        for (int p = 0; p < 8; p++) y[p] = fmaxf(fmaf(acc[p], sc, sh), 0.f);
        float* xin_s = (float*)h2s;   // h2s dead after conv3
        #pragma unroll
        for (int q = 0; q < 4; q++) {
            int ph = q >> 1, pw = q & 1;
            int r1 = ph * 4 + pw * 2;
            float part = fmaxf(y[r1], y[r1 + 1]);
            part = fmaxf(part, __shfl_xor(part, 32));
            if (lane < 32) {
                int f = ((co4 & 3) << 2) + q;
                xin_s[(co4 >> 2) * 16 + f] = fmaf(part, inw[f], inb[f]);
            }
        }
    }
    __syncthreads();
    // ---- sensory synapses: wnum/wden [32 t][19 n] ----
    const float* xin_s = (const float*)h2s;
    for (int idx = tid; idx < 608; idx += 256) {
        int tt = idx / 19, n = idx - tt * 19;
        float nu = 0.f, de = 0.f;
        #pragma unroll
        for (int s = 0; s < 16; s++) {
            float sg = sigmoidf_((xin_s[tt * 16 + s] - smu[s * 19 + n]) * ssig[s * 19 + n]);
            nu = fmaf(par[P_SWME + s * 19 + n], sg, nu);
            de = fmaf(par[P_SWM + s * 19 + n], sg, de);
        }
        wn[((long)b * 32 + tt) * 19 + n] = nu;
        wd[((long)b * 32 + tt) * 19 + n] = de;
    }
}

// ---------------- LTC recurrence: 3 images x 19 neurons per wave ----------------
__global__ __launch_bounds__(256) void k_ltc(
    const float* __restrict__ mu_g, const float* __restrict__ sg_g,
    const float* __restrict__ ws,
    const float* __restrict__ wn, const float* __restrict__ wd,
    const float* __restrict__ outw, const float* __restrict__ outb,
    float* __restrict__ out, int img0, int nimg) {
    const float* par = ws + OFF_PAR;
    int tid = threadIdx.x, wave = tid >> 6, lane = tid & 63;
    int li = lane / 19, j = lane - li * 19;
    if (li > 2) { li = 2; j = 18; }
    int il = blockIdx.x * 12 + wave * 3 + li;
    int ilc = il < nimg ? il : nimg - 1;

    float muj[19], sgj[19], wpj[19], wpej[19];
    #pragma unroll
    for (int i = 0; i < 19; i++) {
        muj[i] = mu_g[i * 19 + j];
        sgj[i] = sg_g[i * 19 + j];
        wpj[i] = par[P_WP + i * 19 + j];
        wpej[i] = par[P_WPE + i * 19 + j];
    }
    float cmt = par[P_CMT + j], gl = par[P_GL + j], glvl = par[P_GLVL + j];
    float v = 0.f;
    for (int t = 0; t < 32; t++) {
        long base = ((long)ilc * 32 + t) * 19 + j;
        float wns = wn[base], wds = wd[base];
        #pragma unroll 1
        for (int u = 0; u < 6; u++) {
            float num = fmaf(cmt, v, glvl) + wns;
            float den = cmt + gl + wds;
            #pragma unroll
            for (int i = 0; i < 19; i++) {
                float vi = __shfl(v, li * 19 + i, 64);
                float sg = sigmoidf_((vi - muj[i]) * sgj[i]);
                num = fmaf(wpej[i], sg, num);
                den = fmaf(wpj[i], sg, den);
            }
            v = num / (den + 1e-8f);
        }
    }
    if (j < 2 && il < nimg && lane < 57)
        out[(long)(img0 + il) * 2 + j] = fmaf(v, outw[j], outb[j]);
}

extern "C" void kernel_launch(void* const* d_in, const int* in_sizes, int n_in,
                              void* d_out, int out_size, void* d_ws, size_t ws_size,
                              hipStream_t stream) {
    const float* x    = (const float*)d_in[0];
    const float* w1   = (const float*)d_in[1];
    const float* b1   = (const float*)d_in[2];
    const float* w2   = (const float*)d_in[3];
    const float* b2   = (const float*)d_in[4];
    const float* g2   = (const float*)d_in[5];
    const float* be2  = (const float*)d_in[6];
    const float* m2   = (const float*)d_in[7];
    const float* v2   = (const float*)d_in[8];
    const float* w3   = (const float*)d_in[9];
    const float* b3   = (const float*)d_in[10];
    const float* w4   = (const float*)d_in[11];
    const float* b4   = (const float*)d_in[12];
    const float* g4   = (const float*)d_in[13];
    const float* be4  = (const float*)d_in[14];
    const float* m4   = (const float*)d_in[15];
    const float* v4   = (const float*)d_in[16];
    const float* inw  = (const float*)d_in[17];
    const float* inb  = (const float*)d_in[18];
    const float* smu  = (const float*)d_in[19];
    const float* ssig = (const float*)d_in[20];
    const float* sw   = (const float*)d_in[21];
    const float* serv = (const float*)d_in[22];
    const float* smk  = (const float*)d_in[23];
    const float* mu_  = (const float*)d_in[24];
    const float* sig_ = (const float*)d_in[25];
    const float* w_   = (const float*)d_in[26];
    const float* erev = (const float*)d_in[27];
    const float* mask = (const float*)d_in[28];
    const float* glk  = (const float*)d_in[29];
    const float* vlk  = (const float*)d_in[30];
    const float* cm   = (const float*)d_in[31];
    const float* outw = (const float*)d_in[32];
    const float* outb = (const float*)d_in[33];
    float* ws = (float*)d_ws;

    k_prep<<<64, 256, 0, stream>>>(w2, w3, w4, sw, serv, smk, w_, erev, mask,
                                   glk, vlk, cm, b2, g2, be2, m2, v2,
                                   b4, g4, be4, m4, v4, ws);

    // auto-size batch chunk: per-image = h2(6272) + wn/wd(1216) floats
    long avail = (long)(ws_size / 4) - OFF_DYN;
    long per = 6272 + 1216;
    int chunk = (int)(avail / per);
    if (chunk > BATCH) chunk = BATCH;
    if (chunk < 1) chunk = 1;

    float* wnp = ws + OFF_DYN;
    float* wdp = wnp + (long)chunk * 608;
    float* h2  = wdp + (long)chunk * 608;

    for (int c0 = 0; c0 < BATCH; c0 += chunk) {
        int n = (BATCH - c0 < chunk) ? (BATCH - c0) : chunk;
        k_conv12<<<n, 256, 0, stream>>>(x + (long)c0 * 784, w1, b1, ws, h2);
        k_conv34s<<<n, 256, 0, stream>>>(h2, b3, inw, inb, smu, ssig, ws, wnp, wdp);
        k_ltc<<<(n + 11) / 12, 256, 0, stream>>>(mu_, sig_, ws, wnp, wdp, outw, outb,
                                                 (float*)d_out, c0, n);
    }
}

// Round 5
// 756.539 us; speedup vs baseline: 2.9754x; 1.1885x over previous
//
#include <hip/hip_runtime.h>

#define BATCH 4096
typedef unsigned short u16_t;

// ---- par sub-offsets (floats) ----
#define P_SWM   0
#define P_SWME  304
#define P_WP    608
#define P_WPE   969
#define P_GL    1330
#define P_GLVL  1349
#define P_CMT   1368
#define P_SC2   1392
#define P_SH2   1424
#define P_SC4   1456
#define P_SH4   1584
// par total 1712, reserve 2048

// ---- workspace layout (float offsets) ----
#define OFF_PAR 0L
#define OFF_B2F 2048L      // bf16 frag conv2 W: [pl2][s9][ln64][j8] = 9216 u16 = 4608 f
#define OFF_B3F 6656L      // bf16 frag conv3 W: [pl2][nt2][s50][ln64][j8] = 102400 u16
#define OFF_B4F 57856L     // bf16 frag conv4 W: [pl2][nt4][s100][ln64][j8] = 409600 u16
#define OFF_DYN 262656L    // then per chunk: wnum[chunk*608], wden[chunk*608], h2[chunk*6272 u32]

typedef __attribute__((ext_vector_type(8))) short short8;
typedef __attribute__((ext_vector_type(16))) float f32x16;
#define MFMA(a, b, c) __builtin_amdgcn_mfma_f32_32x32x16_bf16(a, b, c, 0, 0, 0)

// byte-select: build (w1.lo16<<16)|w0.lo16 and (w1.hi16<<16)|w0.hi16
#define PERM_HI(w1, w0) __builtin_amdgcn_perm((w1), (w0), 0x05040100u)
#define PERM_LO(w1, w0) __builtin_amdgcn_perm((w1), (w0), 0x07060302u)

union U8 { unsigned u[4]; short8 v; };

__device__ __forceinline__ float sigmoidf_(float x) {
    return 1.0f / (1.0f + __expf(-x));
}
__device__ __forceinline__ float softplusf_(float x) { return log1pf(__expf(x)); }

// split fp32 -> packed (hi trunc-bf16 in low16, lo rne-bf16 of residual in high16)
__device__ __forceinline__ unsigned splitpack(float f) {
    unsigned u = __float_as_uint(f);
    float rsd = f - __uint_as_float(u & 0xFFFF0000u);
    unsigned ur = __float_as_uint(rsd);
    ur = ur + 0x7FFFu + ((ur >> 16) & 1u);
    return (u >> 16) | (ur & 0xFFFF0000u);
}
__device__ __forceinline__ u16_t bfhalf(float v, int pl) {
    unsigned u = __float_as_uint(v);
    if (pl == 0) return (u16_t)(u >> 16);
    float rsd = v - __uint_as_float(u & 0xFFFF0000u);
    unsigned ur = __float_as_uint(rsd);
    ur = ur + 0x7FFFu + ((ur >> 16) & 1u);
    return (u16_t)(ur >> 16);
}

// ---------------- prep: derived LTC params + BN folds + weight split/reorder ----------------
__global__ __launch_bounds__(256) void k_prep(
    const float* __restrict__ w2, const float* __restrict__ w3, const float* __restrict__ w4,
    const float* __restrict__ sw, const float* __restrict__ serev, const float* __restrict__ smask,
    const float* __restrict__ w,  const float* __restrict__ erev,  const float* __restrict__ mask,
    const float* __restrict__ gleak, const float* __restrict__ vleak, const float* __restrict__ cm,
    const float* __restrict__ b2, const float* __restrict__ g2, const float* __restrict__ be2,
    const float* __restrict__ m2, const float* __restrict__ v2,
    const float* __restrict__ b4, const float* __restrict__ g4, const float* __restrict__ be4,
    const float* __restrict__ m4, const float* __restrict__ v4,
    float* __restrict__ ws) {
    int gid = blockIdx.x * 256 + threadIdx.x, stride = gridDim.x * 256;
    u16_t* b2f = (u16_t*)(ws + OFF_B2F);
    u16_t* b3f = (u16_t*)(ws + OFF_B3F);
    u16_t* b4f = (u16_t*)(ws + OFF_B4F);
    // conv2 weights, frag order, k = tap*16 + ci
    for (int i = gid; i < 9216; i += stride) {
        int j = i & 7, ln = (i >> 3) & 63;
        int r = i >> 9;
        int s = r % 9, pl = r / 9;
        int k = s * 16 + (ln >> 5) * 8 + j;
        int tap = k >> 4, ci = k & 15;
        int co = ln & 31;
        b2f[i] = bfhalf(w2[(co * 16 + ci) * 9 + tap], pl);
    }
    // conv3 weights, frag order, k = tap*32 + ci
    for (int i = gid; i < 102400; i += stride) {
        int j = i & 7, ln = (i >> 3) & 63;
        int t = i >> 9;
        int s = t % 50, r = t / 50;
        int nt = r & 1, pl = r >> 1;
        int k = s * 16 + (ln >> 5) * 8 + j;
        int tap = k >> 5, ci = k & 31;
        int co = nt * 32 + (ln & 31);
        b3f[i] = bfhalf(w3[(co * 32 + ci) * 25 + tap], pl);
    }
    // conv4 weights, frag order, k = tap*64 + ci
    for (int i = gid; i < 409600; i += stride) {
        int j = i & 7, ln = (i >> 3) & 63;
        int t = i >> 9;
        int s = t % 100, r = t / 100;
        int nt = r & 3, pl = r >> 2;
        int k = s * 16 + (ln >> 5) * 8 + j;
        int tap = k >> 6, ci = k & 63;
        int co = nt * 32 + (ln & 31);
        b4f[i] = bfhalf(w4[(co * 64 + ci) * 25 + tap], pl);
    }
    if (blockIdx.x == 0) {
        float* par = ws + OFF_PAR;
        int tid = threadIdx.x;
        for (int i = tid; i < 304; i += 256) {
            float v_ = softplusf_(sw[i]) * smask[i];
            par[P_SWM + i] = v_;
            par[P_SWME + i] = v_ * serev[i];
        }
        for (int i = tid; i < 361; i += 256) {
            float v_ = softplusf_(w[i]) * mask[i];
            par[P_WP + i] = v_;
            par[P_WPE + i] = v_ * erev[i];
        }
        for (int i = tid; i < 19; i += 256) {
            float g = softplusf_(gleak[i]);
            par[P_GL + i] = g;
            par[P_GLVL + i] = g * vleak[i];
            par[P_CMT + i] = softplusf_(cm[i]) * 6.0f;
        }
        for (int i = tid; i < 32; i += 256) {
            float inv = g2[i] * __frsqrt_rn(v2[i] + 1e-5f);
            par[P_SC2 + i] = inv;
            par[P_SH2 + i] = (b2[i] - m2[i]) * inv + be2[i];
        }
        for (int i = tid; i < 128; i += 256) {
            float inv = g4[i] * __frsqrt_rn(v4[i] + 1e-5f);
            par[P_SC4 + i] = inv;
            par[P_SH4 + i] = (b4[i] - m4[i]) * inv + be4[i];
        }
    }
}

// ---------------- conv1 (VALU) + conv2 (MFMA) ----------------
// h1 in LDS as packed u32 [29 rows][29 cols][17 ch-stride] (zero borders).
// LDS = 14300*4 + 784*4 = 60336 B -> 2 blocks/CU.
__global__ __launch_bounds__(256, 2) void k_conv12(
    const float* __restrict__ x, const float* __restrict__ w1, const float* __restrict__ b1,
    const float* __restrict__ ws, unsigned* __restrict__ h2g) {
    __shared__ float xs[784];
    __shared__ unsigned h1s[14300];   // [r29][c29][17] packed (hi,lo)
    const float* par = ws + OFF_PAR;
    int b = blockIdx.x, tid = threadIdx.x;
    {
        for (int i = tid; i < 784; i += 256) xs[i] = x[(long)b * 784 + i];
        uint4* hz = (uint4*)h1s;
        uint4 z; z.x = z.y = z.z = z.w = 0u;
        for (int i = tid; i < 3575; i += 256) hz[i] = z;
    }
    __syncthreads();
    // conv1: 3x3 s1 p0 -> 16x26x26, ReLU, splitpack into h1s
    {
        int co = tid >> 4, slot = tid & 15;
        float wr[9];
        #pragma unroll
        for (int i = 0; i < 9; i++) wr[i] = w1[co * 9 + i];
        float bb = b1[co];
        for (int k = 0; k < 43; k++) {
            int px = slot + (k << 4);
            if (px >= 676) break;
            int oh = px / 26, ow = px % 26;
            float s = bb;
            #pragma unroll
            for (int kh = 0; kh < 3; kh++)
                #pragma unroll
                for (int kw = 0; kw < 3; kw++)
                    s = fmaf(xs[(oh + kh) * 28 + ow + kw], wr[kh * 3 + kw], s);
            h1s[((oh + 2) * 29 + (ow + 2)) * 17 + co] = splitpack(fmaxf(s, 0.f));
        }
    }
    __syncthreads();
    // conv2 GEMM: C[196px x 32co], K=144 (k = tap*16 + ci), 7 m-tiles over 4 waves
    {
        int wv = tid >> 6, lane = tid & 63;
        int mloc = lane & 31, hf = lane >> 5, half8 = hf * 8;
        const u16_t* B2 = (const u16_t*)(ws + OFF_B2F);
        const short8* pb = (const short8*)B2 + lane;
        float sc = par[P_SC2 + mloc], sh = par[P_SH2 + mloc];
        for (int tix = 0; tix < 2; tix++) {
            int mt = wv + tix * 4;
            if (mt >= 7) break;
            int px = mt * 32 + mloc;
            bool pxok = px < 196;
            int pxc = pxok ? px : 195;
            int oh = pxc / 14, ow = pxc % 14;
            f32x16 acc;
            #pragma unroll
            for (int i = 0; i < 16; i++) acc[i] = 0.f;
            #pragma unroll
            for (int s = 0; s < 9; s++) {
                int kh = s / 3, kw = s % 3;
                int abase = (pxok ? ((oh * 2 + kh) * 29 + (ow * 2 + kw)) * 17 : 0) + half8;
                unsigned w_[8];
                #pragma unroll
                for (int j = 0; j < 8; j++) w_[j] = h1s[abase + j];
                U8 ah, al;
                #pragma unroll
                for (int d = 0; d < 4; d++) {
                    ah.u[d] = PERM_HI(w_[2 * d + 1], w_[2 * d]);
                    al.u[d] = PERM_LO(w_[2 * d + 1], w_[2 * d]);
                }
                short8 bh = pb[s * 64];
                short8 bl = pb[(9 + s) * 64];
                acc = MFMA(ah.v, bh, acc);
                acc = MFMA(ah.v, bl, acc);
                acc = MFMA(al.v, bh, acc);
            }
            #pragma unroll
            for (int r5 = 0; r5 < 16; r5++) {
                int row = (r5 & 3) + 8 * (r5 >> 2) + 4 * hf;
                int pxw = mt * 32 + row;
                if (pxw < 196) {
                    float y = fmaxf(fmaf(acc[r5], sc, sh), 0.f);
                    h2g[(long)b * 6272 + pxw * 32 + mloc] = splitpack(y);
                }
            }
        }
    }
}

// ---- conv3 + conv4 MFMA GEMMs + BN/ReLU/pool/xin + sensory ----
// LDS: h2s [197][34] u32 = 26792 B + h3s [50][66] u32 = 13200 B -> 39992 B, 4 blocks/CU.
__global__ __launch_bounds__(256, 4) void k_conv34s(
    const unsigned* __restrict__ h2g, const float* __restrict__ b3g,
    const float* __restrict__ inw, const float* __restrict__ inb,
    const float* __restrict__ smu, const float* __restrict__ ssig,
    const float* __restrict__ ws,
    float* __restrict__ wn, float* __restrict__ wd) {
    __shared__ unsigned h2s[6698];   // [px196 + zero-row][stride 34]; reused as xin f32 later
    __shared__ unsigned h3s[3300];   // [px49 + zero-row][stride 66]
    const float* par = ws + OFF_PAR;
    int b = blockIdx.x, tid = threadIdx.x;
    {
        const unsigned* src = h2g + (long)b * 6272;
        for (int i = tid; i < 6272; i += 256) {
            int px = i >> 5, ci = i & 31;
            h2s[px * 34 + ci] = src[i];
        }
        if (tid < 34) h2s[196 * 34 + tid] = 0u;
        if (tid < 66) h3s[49 * 66 + tid] = 0u;
    }
    __syncthreads();
    int wv = tid >> 6;
    int lane = tid & 63;
    int mloc = lane & 31, hf = lane >> 5, half8 = hf * 8;

    // ---- conv3 GEMM: C[64px(49) x 64co], K=800 (k = tap*32 + ci) ----
    {
        int mt = wv & 1, nt = wv >> 1;
        int px = mt * 32 + mloc;
        int oh = px / 7, ow = px % 7;
        bool pxok = px < 49;
        int oh2 = oh * 2 - 2, ow2 = ow * 2 - 2;
        int co3 = nt * 32 + mloc;
        float bias = b3g[co3];
        f32x16 acc;
        #pragma unroll
        for (int i = 0; i < 16; i++) acc[i] = bias;
        const u16_t* B3 = (const u16_t*)(ws + OFF_B3F);
        const short8* pbh = (const short8*)(B3 + (long)(nt * 50) * 512) + lane;
        const short8* pbl = (const short8*)(B3 + (long)((2 + nt) * 50) * 512) + lane;
        int s = 0;
        for (int kh = 0; kh < 5; kh++) {
            int ih = oh2 + kh;
            #pragma unroll
            for (int kw = 0; kw < 5; kw++) {
                int iw = ow2 + kw;
                bool ok = pxok && ((unsigned)ih < 14u) && ((unsigned)iw < 14u);
                int rowb = (ok ? (ih * 14 + iw) : 196) * 34;
                #pragma unroll
                for (int sub = 0; sub < 2; sub++) {
                    const uint2* ap = (const uint2*)(h2s + rowb + sub * 16 + half8);
                    uint2 p0 = ap[0], p1 = ap[1], p2 = ap[2], p3 = ap[3];
                    U8 ah, al;
                    ah.u[0] = PERM_HI(p0.y, p0.x); al.u[0] = PERM_LO(p0.y, p0.x);
                    ah.u[1] = PERM_HI(p1.y, p1.x); al.u[1] = PERM_LO(p1.y, p1.x);
                    ah.u[2] = PERM_HI(p2.y, p2.x); al.u[2] = PERM_LO(p2.y, p2.x);
                    ah.u[3] = PERM_HI(p3.y, p3.x); al.u[3] = PERM_LO(p3.y, p3.x);
                    short8 bh = pbh[s * 64];
                    short8 bl = pbl[s * 64];
                    acc = MFMA(ah.v, bh, acc);
                    acc = MFMA(ah.v, bl, acc);
                    acc = MFMA(al.v, bh, acc);
                    s++;
                }
            }
        }
        // epilogue: ReLU, split, write h3 packed [px][co]
        #pragma unroll
        for (int r5 = 0; r5 < 16; r5++) {
            int row = (r5 & 3) + 8 * (r5 >> 2) + 4 * hf;
            int pxw = mt * 32 + row;
            if (pxw < 49) {
                float y = fmaxf(acc[r5], 0.f);
                h3s[pxw * 66 + co3] = splitpack(y);
            }
        }
    }
    __syncthreads();
    // ---- conv4 GEMM: C[32px(16) x 128co], K=1600 (k = tap*64 + ci) ----
    {
        int oh = mloc >> 2, ow = mloc & 3;
        bool pxok = mloc < 16;
        int oh2 = oh * 2 - 2, ow2 = ow * 2 - 2;
        int co4 = wv * 32 + mloc;
        f32x16 acc;
        #pragma unroll
        for (int i = 0; i < 16; i++) acc[i] = 0.f;
        const u16_t* B4 = (const u16_t*)(ws + OFF_B4F);
        const short8* pbh = (const short8*)(B4 + (long)(wv * 100) * 512) + lane;
        const short8* pbl = (const short8*)(B4 + (long)((4 + wv) * 100) * 512) + lane;
        int s = 0;
        for (int kh = 0; kh < 5; kh++) {
            int ih = oh2 + kh;
            #pragma unroll
            for (int kw = 0; kw < 5; kw++) {
                int iw = ow2 + kw;
                bool ok = pxok && ((unsigned)ih < 7u) && ((unsigned)iw < 7u);
                int rowb = (ok ? (ih * 7 + iw) : 49) * 66;
                #pragma unroll
                for (int sub = 0; sub < 4; sub++) {
                    const uint2* ap = (const uint2*)(h3s + rowb + sub * 16 + half8);
                    uint2 p0 = ap[0], p1 = ap[1], p2 = ap[2], p3 = ap[3];
                    U8 ah, al;
                    ah.u[0] = PERM_HI(p0.y, p0.x); al.u[0] = PERM_LO(p0.y, p0.x);
                    ah.u[1] = PERM_HI(p1.y, p1.x); al.u[1] = PERM_LO(p1.y, p1.x);
                    ah.u[2] = PERM_HI(p2.y, p2.x); al.u[2] = PERM_LO(p2.y, p2.x);
                    ah.u[3] = PERM_HI(p3.y, p3.x); al.u[3] = PERM_LO(p3.y, p3.x);
                    short8 bh = pbh[s * 64];
                    short8 bl = pbl[s * 64];
                    acc = MFMA(ah.v, bh, acc);
                    acc = MFMA(ah.v, bl, acc);
                    acc = MFMA(al.v, bh, acc);
                    s++;
                }
            }
        }
        // epilogue: BN+ReLU (regs 0..7 = px 0..15), shfl 2x2 maxpool, xin
        float sc = par[P_SC4 + co4], sh = par[P_SH4 + co4];
        float y[8];
        #pragma unroll
        for (int p = 0; p < 8; p++) y[p] = fmaxf(fmaf(acc[p], sc, sh), 0.f);
        __syncthreads();   // h2s dead; reuse as xin[32][16] f32
        float* xin_s = (float*)h2s;
        #pragma unroll
        for (int q = 0; q < 4; q++) {
            int ph = q >> 1, pw = q & 1;
            int r1 = ph * 4 + pw * 2;
            float part = fmaxf(y[r1], y[r1 + 1]);
            part = fmaxf(part, __shfl_xor(part, 32));
            if (lane < 32) {
                int f = ((co4 & 3) << 2) + q;
                xin_s[(co4 >> 2) * 16 + f] = fmaf(part, inw[f], inb[f]);
            }
        }
    }
    __syncthreads();
    // ---- sensory synapses: wnum/wden [32 t][19 n] ----
    const float* xin_s = (const float*)h2s;
    for (int idx = tid; idx < 608; idx += 256) {
        int tt = idx / 19, n = idx - tt * 19;
        float nu = 0.f, de = 0.f;
        #pragma unroll
        for (int s = 0; s < 16; s++) {
            float sg = sigmoidf_((xin_s[tt * 16 + s] - smu[s * 19 + n]) * ssig[s * 19 + n]);
            nu = fmaf(par[P_SWME + s * 19 + n], sg, nu);
            de = fmaf(par[P_SWM + s * 19 + n], sg, de);
        }
        wn[((long)b * 32 + tt) * 19 + n] = nu;
        wd[((long)b * 32 + tt) * 19 + n] = de;
    }
}

// ---------------- LTC recurrence: 3 images x 19 neurons per wave ----------------
__global__ __launch_bounds__(256) void k_ltc(
    const float* __restrict__ mu_g, const float* __restrict__ sg_g,
    const float* __restrict__ ws,
    const float* __restrict__ wn, const float* __restrict__ wd,
    const float* __restrict__ outw, const float* __restrict__ outb,
    float* __restrict__ out, int img0, int nimg) {
    const float* par = ws + OFF_PAR;
    int tid = threadIdx.x, wave = tid >> 6, lane = tid & 63;
    int li = lane / 19, j = lane - li * 19;
    if (li > 2) { li = 2; j = 18; }
    int il = blockIdx.x * 12 + wave * 3 + li;
    int ilc = il < nimg ? il : nimg - 1;

    float muj[19], sgj[19], wpj[19], wpej[19];
    #pragma unroll
    for (int i = 0; i < 19; i++) {
        muj[i] = mu_g[i * 19 + j];
        sgj[i] = sg_g[i * 19 + j];
        wpj[i] = par[P_WP + i * 19 + j];
        wpej[i] = par[P_WPE + i * 19 + j];
    }
    float cmt = par[P_CMT + j], gl = par[P_GL + j], glvl = par[P_GLVL + j];
    float v = 0.f;
    for (int t = 0; t < 32; t++) {
        long base = ((long)ilc * 32 + t) * 19 + j;
        float wns = wn[base], wds = wd[base];
        #pragma unroll 1
        for (int u = 0; u < 6; u++) {
            float num = fmaf(cmt, v, glvl) + wns;
            float den = cmt + gl + wds;
            #pragma unroll
            for (int i = 0; i < 19; i++) {
                float vi = __shfl(v, li * 19 + i, 64);
                float sg = sigmoidf_((vi - muj[i]) * sgj[i]);
                num = fmaf(wpej[i], sg, num);
                den = fmaf(wpj[i], sg, den);
            }
            v = num / (den + 1e-8f);
        }
    }
    if (j < 2 && il < nimg && lane < 57)
        out[(long)(img0 + il) * 2 + j] = fmaf(v, outw[j], outb[j]);
}

extern "C" void kernel_launch(void* const* d_in, const int* in_sizes, int n_in,
                              void* d_out, int out_size, void* d_ws, size_t ws_size,
                              hipStream_t stream) {
    const float* x    = (const float*)d_in[0];
    const float* w1   = (const float*)d_in[1];
    const float* b1   = (const float*)d_in[2];
    const float* w2   = (const float*)d_in[3];
    const float* b2   = (const float*)d_in[4];
    const float* g2   = (const float*)d_in[5];
    const float* be2  = (const float*)d_in[6];
    const float* m2   = (const float*)d_in[7];
    const float* v2   = (const float*)d_in[8];
    const float* w3   = (const float*)d_in[9];
    const float* b3   = (const float*)d_in[10];
    const float* w4   = (const float*)d_in[11];
    const float* b4   = (const float*)d_in[12];
    const float* g4   = (const float*)d_in[13];
    const float* be4  = (const float*)d_in[14];
    const float* m4   = (const float*)d_in[15];
    const float* v4   = (const float*)d_in[16];
    const float* inw  = (const float*)d_in[17];
    const float* inb  = (const float*)d_in[18];
    const float* smu  = (const float*)d_in[19];
    const float* ssig = (const float*)d_in[20];
    const float* sw   = (const float*)d_in[21];
    const float* serv = (const float*)d_in[22];
    const float* smk  = (const float*)d_in[23];
    const float* mu_  = (const float*)d_in[24];
    const float* sig_ = (const float*)d_in[25];
    const float* w_   = (const float*)d_in[26];
    const float* erev = (const float*)d_in[27];
    const float* mask = (const float*)d_in[28];
    const float* glk  = (const float*)d_in[29];
    const float* vlk  = (const float*)d_in[30];
    const float* cm   = (const float*)d_in[31];
    const float* outw = (const float*)d_in[32];
    const float* outb = (const float*)d_in[33];
    float* ws = (float*)d_ws;

    k_prep<<<64, 256, 0, stream>>>(w2, w3, w4, sw, serv, smk, w_, erev, mask,
                                   glk, vlk, cm, b2, g2, be2, m2, v2,
                                   b4, g4, be4, m4, v4, ws);

    // auto-size batch chunk: per-image = h2(6272 u32) + wn/wd(1216 f32)
    long avail = (long)(ws_size / 4) - OFF_DYN;
    long per = 6272 + 1216;
    int chunk = (int)(avail / per);
    if (chunk > BATCH) chunk = BATCH;
    if (chunk < 1) chunk = 1;

    float* wnp = ws + OFF_DYN;
    float* wdp = wnp + (long)chunk * 608;
    unsigned* h2 = (unsigned*)(wdp + (long)chunk * 608);

    for (int c0 = 0; c0 < BATCH; c0 += chunk) {
        int n = (BATCH - c0 < chunk) ? (BATCH - c0) : chunk;
        k_conv12<<<n, 256, 0, stream>>>(x + (long)c0 * 784, w1, b1, ws, h2);
        k_conv34s<<<n, 256, 0, stream>>>(h2, b3, inw, inb, smu, ssig, ws, wnp, wdp);
        k_ltc<<<(n + 11) / 12, 256, 0, stream>>>(mu_, sig_, ws, wnp, wdp, outw, outb,
                                                 (float*)d_out, c0, n);
    }
}

// Round 6
// 604.276 us; speedup vs baseline: 3.7252x; 1.2520x over previous
//
#include <hip/hip_runtime.h>

#define BATCH 4096
typedef unsigned short u16_t;

// ---- par sub-offsets (floats) ----
#define P_SWM   0
#define P_SWME  304
#define P_WP    608
#define P_WPE   969
#define P_GL    1330
#define P_GLVL  1349
#define P_CMT   1368
#define P_SC2   1392
#define P_SH2   1424
#define P_SC4   1456
#define P_SH4   1584
// par total 1712, reserve 2048

// ---- workspace layout (float offsets) ----
#define OFF_PAR 0L
#define OFF_B2F 2048L      // bf16 frag conv2 W: [pl2][s9][ln64][j8] = 9216 u16 = 4608 f
#define OFF_B3F 6656L      // bf16 frag conv3 W: [pl2][nt2][s50][ln64][j8] = 102400 u16
#define OFF_B4F 57856L     // bf16 frag conv4 W: [pl2][nt4][s100][ln64][j8] = 409600 u16
#define OFF_DYN 262656L    // then per chunk: wnum[chunk*608], wden[chunk*608], h2[chunk*6272 u32]

typedef __attribute__((ext_vector_type(8))) short short8;
typedef __attribute__((ext_vector_type(16))) float f32x16;
#define MFMA(a, b, c) __builtin_amdgcn_mfma_f32_32x32x16_bf16(a, b, c, 0, 0, 0)

// byte-select: build (w1.lo16<<16)|w0.lo16 and (w1.hi16<<16)|w0.hi16
#define PERM_HI(w1, w0) __builtin_amdgcn_perm((w1), (w0), 0x05040100u)
#define PERM_LO(w1, w0) __builtin_amdgcn_perm((w1), (w0), 0x07060302u)

union U8 { unsigned u[4]; short8 v; };

__device__ __forceinline__ float sigmoidf_(float x) {
    return 1.0f / (1.0f + __expf(-x));
}
__device__ __forceinline__ float softplusf_(float x) { return log1pf(__expf(x)); }

// split fp32 -> packed (hi trunc-bf16 in low16, lo rne-bf16 of residual in high16)
__device__ __forceinline__ unsigned splitpack(float f) {
    unsigned u = __float_as_uint(f);
    float rsd = f - __uint_as_float(u & 0xFFFF0000u);
    unsigned ur = __float_as_uint(rsd);
    ur = ur + 0x7FFFu + ((ur >> 16) & 1u);
    return (u >> 16) | (ur & 0xFFFF0000u);
}
__device__ __forceinline__ u16_t bfhalf(float v, int pl) {
    unsigned u = __float_as_uint(v);
    if (pl == 0) return (u16_t)(u >> 16);
    float rsd = v - __uint_as_float(u & 0xFFFF0000u);
    unsigned ur = __float_as_uint(rsd);
    ur = ur + 0x7FFFu + ((ur >> 16) & 1u);
    return (u16_t)(ur >> 16);
}

// ---------------- prep: derived LTC params + BN folds + weight split/reorder ----------------
__global__ __launch_bounds__(256) void k_prep(
    const float* __restrict__ w2, const float* __restrict__ w3, const float* __restrict__ w4,
    const float* __restrict__ sw, const float* __restrict__ serev, const float* __restrict__ smask,
    const float* __restrict__ w,  const float* __restrict__ erev,  const float* __restrict__ mask,
    const float* __restrict__ gleak, const float* __restrict__ vleak, const float* __restrict__ cm,
    const float* __restrict__ b2, const float* __restrict__ g2, const float* __restrict__ be2,
    const float* __restrict__ m2, const float* __restrict__ v2,
    const float* __restrict__ b4, const float* __restrict__ g4, const float* __restrict__ be4,
    const float* __restrict__ m4, const float* __restrict__ v4,
    float* __restrict__ ws) {
    int gid = blockIdx.x * 256 + threadIdx.x, stride = gridDim.x * 256;
    u16_t* b2f = (u16_t*)(ws + OFF_B2F);
    u16_t* b3f = (u16_t*)(ws + OFF_B3F);
    u16_t* b4f = (u16_t*)(ws + OFF_B4F);
    // conv2 weights, frag order, k = tap*16 + ci
    for (int i = gid; i < 9216; i += stride) {
        int j = i & 7, ln = (i >> 3) & 63;
        int r = i >> 9;
        int s = r % 9, pl = r / 9;
        int k = s * 16 + (ln >> 5) * 8 + j;
        int tap = k >> 4, ci = k & 15;
        int co = ln & 31;
        b2f[i] = bfhalf(w2[(co * 16 + ci) * 9 + tap], pl);
    }
    // conv3 weights, frag order, k = tap*32 + ci
    for (int i = gid; i < 102400; i += stride) {
        int j = i & 7, ln = (i >> 3) & 63;
        int t = i >> 9;
        int s = t % 50, r = t / 50;
        int nt = r & 1, pl = r >> 1;
        int k = s * 16 + (ln >> 5) * 8 + j;
        int tap = k >> 5, ci = k & 31;
        int co = nt * 32 + (ln & 31);
        b3f[i] = bfhalf(w3[(co * 32 + ci) * 25 + tap], pl);
    }
    // conv4 weights, frag order, k = tap*64 + ci
    for (int i = gid; i < 409600; i += stride) {
        int j = i & 7, ln = (i >> 3) & 63;
        int t = i >> 9;
        int s = t % 100, r = t / 100;
        int nt = r & 3, pl = r >> 2;
        int k = s * 16 + (ln >> 5) * 8 + j;
        int tap = k >> 6, ci = k & 63;
        int co = nt * 32 + (ln & 31);
        b4f[i] = bfhalf(w4[(co * 64 + ci) * 25 + tap], pl);
    }
    if (blockIdx.x == 0) {
        float* par = ws + OFF_PAR;
        int tid = threadIdx.x;
        for (int i = tid; i < 304; i += 256) {
            float v_ = softplusf_(sw[i]) * smask[i];
            par[P_SWM + i] = v_;
            par[P_SWME + i] = v_ * serev[i];
        }
        for (int i = tid; i < 361; i += 256) {
            float v_ = softplusf_(w[i]) * mask[i];
            par[P_WP + i] = v_;
            par[P_WPE + i] = v_ * erev[i];
        }
        for (int i = tid; i < 19; i += 256) {
            float g = softplusf_(gleak[i]);
            par[P_GL + i] = g;
            par[P_GLVL + i] = g * vleak[i];
            par[P_CMT + i] = softplusf_(cm[i]) * 6.0f;
        }
        for (int i = tid; i < 32; i += 256) {
            float inv = g2[i] * __frsqrt_rn(v2[i] + 1e-5f);
            par[P_SC2 + i] = inv;
            par[P_SH2 + i] = (b2[i] - m2[i]) * inv + be2[i];
        }
        for (int i = tid; i < 128; i += 256) {
            float inv = g4[i] * __frsqrt_rn(v4[i] + 1e-5f);
            par[P_SC4 + i] = inv;
            par[P_SH4 + i] = (b4[i] - m4[i]) * inv + be4[i];
        }
    }
}

// ---------------- conv1 (VALU) + conv2 (MFMA) ----------------
// h1 in LDS as packed u32 [29 rows][29 cols][17 ch-stride] (zero borders).
// LDS = 14300*4 + 784*4 = 60336 B -> 2 blocks/CU.
__global__ __launch_bounds__(256, 2) void k_conv12(
    const float* __restrict__ x, const float* __restrict__ w1, const float* __restrict__ b1,
    const float* __restrict__ ws, unsigned* __restrict__ h2g) {
    __shared__ float xs[784];
    __shared__ unsigned h1s[14300];   // [r29][c29][17] packed (hi,lo)
    const float* par = ws + OFF_PAR;
    int b = blockIdx.x, tid = threadIdx.x;
    {
        for (int i = tid; i < 784; i += 256) xs[i] = x[(long)b * 784 + i];
        uint4* hz = (uint4*)h1s;
        uint4 z; z.x = z.y = z.z = z.w = 0u;
        for (int i = tid; i < 3575; i += 256) hz[i] = z;
    }
    __syncthreads();
    // conv1: 3x3 s1 p0 -> 16x26x26, ReLU, splitpack into h1s
    {
        int co = tid >> 4, slot = tid & 15;
        float wr[9];
        #pragma unroll
        for (int i = 0; i < 9; i++) wr[i] = w1[co * 9 + i];
        float bb = b1[co];
        for (int k = 0; k < 43; k++) {
            int px = slot + (k << 4);
            if (px >= 676) break;
            int oh = px / 26, ow = px % 26;
            float s = bb;
            #pragma unroll
            for (int kh = 0; kh < 3; kh++)
                #pragma unroll
                for (int kw = 0; kw < 3; kw++)
                    s = fmaf(xs[(oh + kh) * 28 + ow + kw], wr[kh * 3 + kw], s);
            h1s[((oh + 2) * 29 + (ow + 2)) * 17 + co] = splitpack(fmaxf(s, 0.f));
        }
    }
    __syncthreads();
    // conv2 GEMM: C[196px x 32co], K=144 (k = tap*16 + ci), 7 m-tiles over 4 waves
    {
        int wv = tid >> 6, lane = tid & 63;
        int mloc = lane & 31, hf = lane >> 5, half8 = hf * 8;
        const u16_t* B2 = (const u16_t*)(ws + OFF_B2F);
        const short8* pb = (const short8*)B2 + lane;
        float sc = par[P_SC2 + mloc], sh = par[P_SH2 + mloc];
        for (int tix = 0; tix < 2; tix++) {
            int mt = wv + tix * 4;
            if (mt >= 7) break;
            int px = mt * 32 + mloc;
            bool pxok = px < 196;
            int pxc = pxok ? px : 195;
            int oh = pxc / 14, ow = pxc % 14;
            f32x16 acc;
            #pragma unroll
            for (int i = 0; i < 16; i++) acc[i] = 0.f;
            #pragma unroll
            for (int s = 0; s < 9; s++) {
                int kh = s / 3, kw = s % 3;
                int abase = (pxok ? ((oh * 2 + kh) * 29 + (ow * 2 + kw)) * 17 : 0) + half8;
                unsigned w_[8];
                #pragma unroll
                for (int j = 0; j < 8; j++) w_[j] = h1s[abase + j];
                U8 ah, al;
                #pragma unroll
                for (int d = 0; d < 4; d++) {
                    ah.u[d] = PERM_HI(w_[2 * d + 1], w_[2 * d]);
                    al.u[d] = PERM_LO(w_[2 * d + 1], w_[2 * d]);
                }
                short8 bh = pb[s * 64];
                short8 bl = pb[(9 + s) * 64];
                acc = MFMA(ah.v, bh, acc);
                acc = MFMA(ah.v, bl, acc);
                acc = MFMA(al.v, bh, acc);
            }
            #pragma unroll
            for (int r5 = 0; r5 < 16; r5++) {
                int row = (r5 & 3) + 8 * (r5 >> 2) + 4 * hf;
                int pxw = mt * 32 + row;
                if (pxw < 196) {
                    float y = fmaxf(fmaf(acc[r5], sc, sh), 0.f);
                    h2g[(long)b * 6272 + pxw * 32 + mloc] = splitpack(y);
                }
            }
        }
    }
}

// ---- conv3 + conv4 MFMA GEMMs + BN/ReLU/pool/xin + sensory ----
// LDS: h2s [197][34] u32 = 26792 B + h3s [50][66] u32 = 13200 B -> 39992 B, 4 blocks/CU.
__global__ __launch_bounds__(256, 4) void k_conv34s(
    const unsigned* __restrict__ h2g, const float* __restrict__ b3g,
    const float* __restrict__ inw, const float* __restrict__ inb,
    const float* __restrict__ smu, const float* __restrict__ ssig,
    const float* __restrict__ ws,
    float* __restrict__ wn, float* __restrict__ wd) {
    __shared__ unsigned h2s[6698];   // [px196 + zero-row][stride 34]; reused as xin f32 later
    __shared__ unsigned h3s[3300];   // [px49 + zero-row][stride 66]
    const float* par = ws + OFF_PAR;
    int b = blockIdx.x, tid = threadIdx.x;
    {
        const unsigned* src = h2g + (long)b * 6272;
        for (int i = tid; i < 6272; i += 256) {
            int px = i >> 5, ci = i & 31;
            h2s[px * 34 + ci] = src[i];
        }
        if (tid < 34) h2s[196 * 34 + tid] = 0u;
        if (tid < 66) h3s[49 * 66 + tid] = 0u;
    }
    __syncthreads();
    int wv = tid >> 6;
    int lane = tid & 63;
    int mloc = lane & 31, hf = lane >> 5, half8 = hf * 8;

    // ---- conv3 GEMM: C[64px(49) x 64co], K=800 (k = tap*32 + ci) ----
    {
        int mt = wv & 1, nt = wv >> 1;
        int px = mt * 32 + mloc;
        int oh = px / 7, ow = px % 7;
        bool pxok = px < 49;
        int oh2 = oh * 2 - 2, ow2 = ow * 2 - 2;
        int co3 = nt * 32 + mloc;
        float bias = b3g[co3];
        f32x16 acc;
        #pragma unroll
        for (int i = 0; i < 16; i++) acc[i] = bias;
        const u16_t* B3 = (const u16_t*)(ws + OFF_B3F);
        const short8* pbh = (const short8*)(B3 + (long)(nt * 50) * 512) + lane;
        const short8* pbl = (const short8*)(B3 + (long)((2 + nt) * 50) * 512) + lane;
        int s = 0;
        for (int kh = 0; kh < 5; kh++) {
            int ih = oh2 + kh;
            #pragma unroll
            for (int kw = 0; kw < 5; kw++) {
                int iw = ow2 + kw;
                bool ok = pxok && ((unsigned)ih < 14u) && ((unsigned)iw < 14u);
                int rowb = (ok ? (ih * 14 + iw) : 196) * 34;
                #pragma unroll
                for (int sub = 0; sub < 2; sub++) {
                    const uint2* ap = (const uint2*)(h2s + rowb + sub * 16 + half8);
                    uint2 p0 = ap[0], p1 = ap[1], p2 = ap[2], p3 = ap[3];
                    U8 ah, al;
                    ah.u[0] = PERM_HI(p0.y, p0.x); al.u[0] = PERM_LO(p0.y, p0.x);
                    ah.u[1] = PERM_HI(p1.y, p1.x); al.u[1] = PERM_LO(p1.y, p1.x);
                    ah.u[2] = PERM_HI(p2.y, p2.x); al.u[2] = PERM_LO(p2.y, p2.x);
                    ah.u[3] = PERM_HI(p3.y, p3.x); al.u[3] = PERM_LO(p3.y, p3.x);
                    short8 bh = pbh[s * 64];
                    short8 bl = pbl[s * 64];
                    acc = MFMA(ah.v, bh, acc);
                    acc = MFMA(ah.v, bl, acc);
                    acc = MFMA(al.v, bh, acc);
                    s++;
                }
            }
        }
        // epilogue: ReLU, split, write h3 packed [px][co]
        #pragma unroll
        for (int r5 = 0; r5 < 16; r5++) {
            int row = (r5 & 3) + 8 * (r5 >> 2) + 4 * hf;
            int pxw = mt * 32 + row;
            if (pxw < 49) {
                float y = fmaxf(acc[r5], 0.f);
                h3s[pxw * 66 + co3] = splitpack(y);
            }
        }
    }
    __syncthreads();
    // ---- conv4 GEMM: C[32px(16) x 128co], K=1600 (k = tap*64 + ci) ----
    {
        int oh = mloc >> 2, ow = mloc & 3;
        bool pxok = mloc < 16;
        int oh2 = oh * 2 - 2, ow2 = ow * 2 - 2;
        int co4 = wv * 32 + mloc;
        f32x16 acc;
        #pragma unroll
        for (int i = 0; i < 16; i++) acc[i] = 0.f;
        const u16_t* B4 = (const u16_t*)(ws + OFF_B4F);
        const short8* pbh = (const short8*)(B4 + (long)(wv * 100) * 512) + lane;
        const short8* pbl = (const short8*)(B4 + (long)((4 + wv) * 100) * 512) + lane;
        int s = 0;
        for (int kh = 0; kh < 5; kh++) {
            int ih = oh2 + kh;
            #pragma unroll
            for (int kw = 0; kw < 5; kw++) {
                int iw = ow2 + kw;
                bool ok = pxok && ((unsigned)ih < 7u) && ((unsigned)iw < 7u);
                int rowb = (ok ? (ih * 7 + iw) : 49) * 66;
                #pragma unroll
                for (int sub = 0; sub < 4; sub++) {
                    const uint2* ap = (const uint2*)(h3s + rowb + sub * 16 + half8);
                    uint2 p0 = ap[0], p1 = ap[1], p2 = ap[2], p3 = ap[3];
                    U8 ah, al;
                    ah.u[0] = PERM_HI(p0.y, p0.x); al.u[0] = PERM_LO(p0.y, p0.x);
                    ah.u[1] = PERM_HI(p1.y, p1.x); al.u[1] = PERM_LO(p1.y, p1.x);
                    ah.u[2] = PERM_HI(p2.y, p2.x); al.u[2] = PERM_LO(p2.y, p2.x);
                    ah.u[3] = PERM_HI(p3.y, p3.x); al.u[3] = PERM_LO(p3.y, p3.x);
                    short8 bh = pbh[s * 64];
                    short8 bl = pbl[s * 64];
                    acc = MFMA(ah.v, bh, acc);
                    acc = MFMA(ah.v, bl, acc);
                    acc = MFMA(al.v, bh, acc);
                    s++;
                }
            }
        }
        // epilogue: BN+ReLU (regs 0..7 = px 0..15), shfl 2x2 maxpool, xin
        float sc = par[P_SC4 + co4], sh = par[P_SH4 + co4];
        float y[8];
        #pragma unroll
        for (int p = 0; p < 8; p++) y[p] = fmaxf(fmaf(acc[p], sc, sh), 0.f);
        __syncthreads();   // h2s dead; reuse as xin[32][16] f32
        float* xin_s = (float*)h2s;
        #pragma unroll
        for (int q = 0; q < 4; q++) {
            int ph = q >> 1, pw = q & 1;
            int r1 = ph * 4 + pw * 2;
            float part = fmaxf(y[r1], y[r1 + 1]);
            part = fmaxf(part, __shfl_xor(part, 32));
            if (lane < 32) {
                int f = ((co4 & 3) << 2) + q;
                xin_s[(co4 >> 2) * 16 + f] = fmaf(part, inw[f], inb[f]);
            }
        }
    }
    __syncthreads();
    // ---- sensory synapses: wnum/wden [32 t][19 n] ----
    const float* xin_s = (const float*)h2s;
    for (int idx = tid; idx < 608; idx += 256) {
        int tt = idx / 19, n = idx - tt * 19;
        float nu = 0.f, de = 0.f;
        #pragma unroll
        for (int s = 0; s < 16; s++) {
            float sg = sigmoidf_((xin_s[tt * 16 + s] - smu[s * 19 + n]) * ssig[s * 19 + n]);
            nu = fmaf(par[P_SWME + s * 19 + n], sg, nu);
            de = fmaf(par[P_SWM + s * 19 + n], sg, de);
        }
        wn[((long)b * 32 + tt) * 19 + n] = nu;
        wd[((long)b * 32 + tt) * 19 + n] = de;
    }
}

// ---------------- LTC recurrence: 3 images x 19 neurons per wave ----------------
// __launch_bounds__(256,2): VGPR cap 256 so the 4x19 param arrays stay register-
// resident (default heuristic capped at 60 VGPR -> per-unfold scratch reloads).
__global__ __launch_bounds__(256, 2) void k_ltc(
    const float* __restrict__ mu_g, const float* __restrict__ sg_g,
    const float* __restrict__ ws,
    const float* __restrict__ wn, const float* __restrict__ wd,
    const float* __restrict__ outw, const float* __restrict__ outb,
    float* __restrict__ out, int img0, int nimg) {
    const float* par = ws + OFF_PAR;
    int tid = threadIdx.x, wave = tid >> 6, lane = tid & 63;
    int li = lane / 19, j = lane - li * 19;
    if (li > 2) { li = 2; j = 18; }
    int il = blockIdx.x * 12 + wave * 3 + li;
    int ilc = il < nimg ? il : nimg - 1;

    const float L2E = 1.44269504f;
    // sigmoid((v-mu)*sig) = rcp(1 + exp2(v*a + b)), a = -sig*log2e, b = mu*sig*log2e
    float aj[19], bj[19], wpj[19], wpej[19];
    #pragma unroll
    for (int i = 0; i < 19; i++) {
        float mu = mu_g[i * 19 + j];
        float sg = sg_g[i * 19 + j];
        aj[i] = -sg * L2E;
        bj[i] = mu * sg * L2E;
        wpj[i] = par[P_WP + i * 19 + j];
        wpej[i] = par[P_WPE + i * 19 + j];
    }
    float cmt = par[P_CMT + j], gl = par[P_GL + j], glvl = par[P_GLVL + j];
    float v = 0.f;
    long base0 = (long)ilc * 608 + j;
    float wns = wn[base0], wds = wd[base0];
    for (int t = 0; t < 32; t++) {
        // prefetch next t's inputs while this t's unfolds run
        float wns_n = 0.f, wds_n = 0.f;
        if (t < 31) {
            long basen = base0 + (t + 1) * 19;
            wns_n = wn[basen];
            wds_n = wd[basen];
        }
        #pragma unroll 1
        for (int u = 0; u < 6; u++) {
            float n0 = 0.f, n1 = 0.f, d0 = 0.f, d1 = 0.f;
            #pragma unroll
            for (int i = 0; i < 19; i++) {
                float vi = __shfl(v, li * 19 + i, 64);
                float e = __builtin_amdgcn_exp2f(fmaf(vi, aj[i], bj[i]));
                float s = __builtin_amdgcn_rcpf(1.0f + e);
                if (i & 1) { n1 = fmaf(wpej[i], s, n1); d1 = fmaf(wpj[i], s, d1); }
                else       { n0 = fmaf(wpej[i], s, n0); d0 = fmaf(wpj[i], s, d0); }
            }
            float num = fmaf(cmt, v, glvl) + wns + (n0 + n1);
            float den = cmt + gl + wds + (d0 + d1);
            v = num * __builtin_amdgcn_rcpf(den + 1e-8f);
        }
        wns = wns_n; wds = wds_n;
    }
    if (j < 2 && il < nimg && lane < 57)
        out[(long)(img0 + il) * 2 + j] = fmaf(v, outw[j], outb[j]);
}

extern "C" void kernel_launch(void* const* d_in, const int* in_sizes, int n_in,
                              void* d_out, int out_size, void* d_ws, size_t ws_size,
                              hipStream_t stream) {
    const float* x    = (const float*)d_in[0];
    const float* w1   = (const float*)d_in[1];
    const float* b1   = (const float*)d_in[2];
    const float* w2   = (const float*)d_in[3];
    const float* b2   = (const float*)d_in[4];
    const float* g2   = (const float*)d_in[5];
    const float* be2  = (const float*)d_in[6];
    const float* m2   = (const float*)d_in[7];
    const float* v2   = (const float*)d_in[8];
    const float* w3   = (const float*)d_in[9];
    const float* b3   = (const float*)d_in[10];
    const float* w4   = (const float*)d_in[11];
    const float* b4   = (const float*)d_in[12];
    const float* g4   = (const float*)d_in[13];
    const float* be4  = (const float*)d_in[14];
    const float* m4   = (const float*)d_in[15];
    const float* v4   = (const float*)d_in[16];
    const float* inw  = (const float*)d_in[17];
    const float* inb  = (const float*)d_in[18];
    const float* smu  = (const float*)d_in[19];
    const float* ssig = (const float*)d_in[20];
    const float* sw   = (const float*)d_in[21];
    const float* serv = (const float*)d_in[22];
    const float* smk  = (const float*)d_in[23];
    const float* mu_  = (const float*)d_in[24];
    const float* sig_ = (const float*)d_in[25];
    const float* w_   = (const float*)d_in[26];
    const float* erev = (const float*)d_in[27];
    const float* mask = (const float*)d_in[28];
    const float* glk  = (const float*)d_in[29];
    const float* vlk  = (const float*)d_in[30];
    const float* cm   = (const float*)d_in[31];
    const float* outw = (const float*)d_in[32];
    const float* outb = (const float*)d_in[33];
    float* ws = (float*)d_ws;

    k_prep<<<64, 256, 0, stream>>>(w2, w3, w4, sw, serv, smk, w_, erev, mask,
                                   glk, vlk, cm, b2, g2, be2, m2, v2,
                                   b4, g4, be4, m4, v4, ws);

    // auto-size batch chunk: per-image = h2(6272 u32) + wn/wd(1216 f32)
    long avail = (long)(ws_size / 4) - OFF_DYN;
    long per = 6272 + 1216;
    int chunk = (int)(avail / per);
    if (chunk > BATCH) chunk = BATCH;
    if (chunk < 1) chunk = 1;

    float* wnp = ws + OFF_DYN;
    float* wdp = wnp + (long)chunk * 608;
    unsigned* h2 = (unsigned*)(wdp + (long)chunk * 608);

    for (int c0 = 0; c0 < BATCH; c0 += chunk) {
        int n = (BATCH - c0 < chunk) ? (BATCH - c0) : chunk;
        k_conv12<<<n, 256, 0, stream>>>(x + (long)c0 * 784, w1, b1, ws, h2);
        k_conv34s<<<n, 256, 0, stream>>>(h2, b3, inw, inb, smu, ssig, ws, wnp, wdp);
        k_ltc<<<(n + 11) / 12, 256, 0, stream>>>(mu_, sig_, ws, wnp, wdp, outw, outb,
                                                 (float*)d_out, c0, n);
    }
}

// Round 7
// 602.786 us; speedup vs baseline: 3.7344x; 1.0025x over previous
//
#include <hip/hip_runtime.h>

#define BATCH 4096
typedef unsigned short u16_t;

// ---- par sub-offsets (floats) ----
#define P_SWM   0
#define P_SWME  304
#define P_WP    608
#define P_WPE   969
#define P_GL    1330
#define P_GLVL  1349
#define P_CMT   1368
#define P_SC2   1392
#define P_SH2   1424
#define P_SC4   1456
#define P_SH4   1584
// par total 1712, reserve 2048

// ---- workspace layout (float offsets) ----
#define OFF_PAR 0L
#define OFF_B2F 2048L      // bf16 frag conv2 W: [pl2][s9][ln64][j8] = 9216 u16 = 4608 f
#define OFF_B3F 6656L      // bf16 frag conv3 W: [pl2][nt2][s50][ln64][j8] = 102400 u16
#define OFF_B4F 57856L     // bf16 frag conv4 W: [pl2][nt4][s100][ln64][j8] = 409600 u16
#define OFF_DYN 262656L    // then per chunk: wnum[chunk*608], wden[chunk*608], h2[chunk*6272 u32]

typedef __attribute__((ext_vector_type(8))) short short8;
typedef __attribute__((ext_vector_type(16))) float f32x16;
#define MFMA(a, b, c) __builtin_amdgcn_mfma_f32_32x32x16_bf16(a, b, c, 0, 0, 0)

// byte-select: build (w1.lo16<<16)|w0.lo16 and (w1.hi16<<16)|w0.hi16
#define PERM_HI(w1, w0) __builtin_amdgcn_perm((w1), (w0), 0x05040100u)
#define PERM_LO(w1, w0) __builtin_amdgcn_perm((w1), (w0), 0x07060302u)

union U8 { unsigned u[4]; short8 v; };

__device__ __forceinline__ float sigmoidf_(float x) {
    return 1.0f / (1.0f + __expf(-x));
}
__device__ __forceinline__ float softplusf_(float x) { return log1pf(__expf(x)); }

// split fp32 -> packed (hi trunc-bf16 in low16, lo rne-bf16 of residual in high16)
__device__ __forceinline__ unsigned splitpack(float f) {
    unsigned u = __float_as_uint(f);
    float rsd = f - __uint_as_float(u & 0xFFFF0000u);
    unsigned ur = __float_as_uint(rsd);
    ur = ur + 0x7FFFu + ((ur >> 16) & 1u);
    return (u >> 16) | (ur & 0xFFFF0000u);
}
__device__ __forceinline__ u16_t bfhalf(float v, int pl) {
    unsigned u = __float_as_uint(v);
    if (pl == 0) return (u16_t)(u >> 16);
    float rsd = v - __uint_as_float(u & 0xFFFF0000u);
    unsigned ur = __float_as_uint(rsd);
    ur = ur + 0x7FFFu + ((ur >> 16) & 1u);
    return (u16_t)(ur >> 16);
}

// ---------------- prep: derived LTC params + BN folds + weight split/reorder ----------------
__global__ __launch_bounds__(256) void k_prep(
    const float* __restrict__ w2, const float* __restrict__ w3, const float* __restrict__ w4,
    const float* __restrict__ sw, const float* __restrict__ serev, const float* __restrict__ smask,
    const float* __restrict__ w,  const float* __restrict__ erev,  const float* __restrict__ mask,
    const float* __restrict__ gleak, const float* __restrict__ vleak, const float* __restrict__ cm,
    const float* __restrict__ b2, const float* __restrict__ g2, const float* __restrict__ be2,
    const float* __restrict__ m2, const float* __restrict__ v2,
    const float* __restrict__ b4, const float* __restrict__ g4, const float* __restrict__ be4,
    const float* __restrict__ m4, const float* __restrict__ v4,
    float* __restrict__ ws) {
    int gid = blockIdx.x * 256 + threadIdx.x, stride = gridDim.x * 256;
    u16_t* b2f = (u16_t*)(ws + OFF_B2F);
    u16_t* b3f = (u16_t*)(ws + OFF_B3F);
    u16_t* b4f = (u16_t*)(ws + OFF_B4F);
    // conv2 weights, frag order, k = tap*16 + ci
    for (int i = gid; i < 9216; i += stride) {
        int j = i & 7, ln = (i >> 3) & 63;
        int r = i >> 9;
        int s = r % 9, pl = r / 9;
        int k = s * 16 + (ln >> 5) * 8 + j;
        int tap = k >> 4, ci = k & 15;
        int co = ln & 31;
        b2f[i] = bfhalf(w2[(co * 16 + ci) * 9 + tap], pl);
    }
    // conv3 weights, frag order, k = tap*32 + ci
    for (int i = gid; i < 102400; i += stride) {
        int j = i & 7, ln = (i >> 3) & 63;
        int t = i >> 9;
        int s = t % 50, r = t / 50;
        int nt = r & 1, pl = r >> 1;
        int k = s * 16 + (ln >> 5) * 8 + j;
        int tap = k >> 5, ci = k & 31;
        int co = nt * 32 + (ln & 31);
        b3f[i] = bfhalf(w3[(co * 32 + ci) * 25 + tap], pl);
    }
    // conv4 weights, frag order, k = tap*64 + ci
    for (int i = gid; i < 409600; i += stride) {
        int j = i & 7, ln = (i >> 3) & 63;
        int t = i >> 9;
        int s = t % 100, r = t / 100;
        int nt = r & 3, pl = r >> 2;
        int k = s * 16 + (ln >> 5) * 8 + j;
        int tap = k >> 6, ci = k & 63;
        int co = nt * 32 + (ln & 31);
        b4f[i] = bfhalf(w4[(co * 64 + ci) * 25 + tap], pl);
    }
    if (blockIdx.x == 0) {
        float* par = ws + OFF_PAR;
        int tid = threadIdx.x;
        for (int i = tid; i < 304; i += 256) {
            float v_ = softplusf_(sw[i]) * smask[i];
            par[P_SWM + i] = v_;
            par[P_SWME + i] = v_ * serev[i];
        }
        for (int i = tid; i < 361; i += 256) {
            float v_ = softplusf_(w[i]) * mask[i];
            par[P_WP + i] = v_;
            par[P_WPE + i] = v_ * erev[i];
        }
        for (int i = tid; i < 19; i += 256) {
            float g = softplusf_(gleak[i]);
            par[P_GL + i] = g;
            par[P_GLVL + i] = g * vleak[i];
            par[P_CMT + i] = softplusf_(cm[i]) * 6.0f;
        }
        for (int i = tid; i < 32; i += 256) {
            float inv = g2[i] * __frsqrt_rn(v2[i] + 1e-5f);
            par[P_SC2 + i] = inv;
            par[P_SH2 + i] = (b2[i] - m2[i]) * inv + be2[i];
        }
        for (int i = tid; i < 128; i += 256) {
            float inv = g4[i] * __frsqrt_rn(v4[i] + 1e-5f);
            par[P_SC4 + i] = inv;
            par[P_SH4 + i] = (b4[i] - m4[i]) * inv + be4[i];
        }
    }
}

// ---------------- conv1 (VALU) + conv2 (MFMA), 512 threads ----------------
// h1 in LDS as packed u32 [29 rows][29 cols][17 ch-stride] (zero borders).
// LDS = 60336 B -> 2 blocks/CU x 8 waves = 16 waves/CU.
__global__ __launch_bounds__(512, 4) void k_conv12(
    const float* __restrict__ x, const float* __restrict__ w1, const float* __restrict__ b1,
    const float* __restrict__ ws, unsigned* __restrict__ h2g) {
    __shared__ float xs[784];
    __shared__ unsigned h1s[14300];   // [r29][c29][17] packed (hi,lo)
    const float* par = ws + OFF_PAR;
    int b = blockIdx.x, tid = threadIdx.x;
    {
        for (int i = tid; i < 784; i += 512) xs[i] = x[(long)b * 784 + i];
        uint4* hz = (uint4*)h1s;
        uint4 z; z.x = z.y = z.z = z.w = 0u;
        for (int i = tid; i < 3575; i += 512) hz[i] = z;
    }
    __syncthreads();
    // conv1: 3x3 s1 p0 -> 16x26x26, ReLU, splitpack into h1s
    {
        int co = tid >> 5, slot = tid & 31;
        float wr[9];
        #pragma unroll
        for (int i = 0; i < 9; i++) wr[i] = w1[co * 9 + i];
        float bb = b1[co];
        for (int k = 0; k < 22; k++) {
            int px = slot + (k << 5);
            if (px >= 676) break;
            int oh = px / 26, ow = px % 26;
            float s = bb;
            #pragma unroll
            for (int kh = 0; kh < 3; kh++)
                #pragma unroll
                for (int kw = 0; kw < 3; kw++)
                    s = fmaf(xs[(oh + kh) * 28 + ow + kw], wr[kh * 3 + kw], s);
            h1s[((oh + 2) * 29 + (ow + 2)) * 17 + co] = splitpack(fmaxf(s, 0.f));
        }
    }
    __syncthreads();
    // conv2 GEMM: C[196px x 32co], K=144 (k = tap*16 + ci), 7 m-tiles, 1 per wave
    {
        int wv = tid >> 6, lane = tid & 63;
        int mloc = lane & 31, hf = lane >> 5, half8 = hf * 8;
        const u16_t* B2 = (const u16_t*)(ws + OFF_B2F);
        const short8* pb = (const short8*)B2 + lane;
        float sc = par[P_SC2 + mloc], sh = par[P_SH2 + mloc];
        int mt = wv;
        if (mt < 7) {
            int px = mt * 32 + mloc;
            bool pxok = px < 196;
            int pxc = pxok ? px : 195;
            int oh = pxc / 14, ow = pxc % 14;
            f32x16 acc;
            #pragma unroll
            for (int i = 0; i < 16; i++) acc[i] = 0.f;
            #pragma unroll
            for (int s = 0; s < 9; s++) {
                int kh = s / 3, kw = s % 3;
                int abase = (pxok ? ((oh * 2 + kh) * 29 + (ow * 2 + kw)) * 17 : 0) + half8;
                unsigned w_[8];
                #pragma unroll
                for (int j = 0; j < 8; j++) w_[j] = h1s[abase + j];
                U8 ah, al;
                #pragma unroll
                for (int d = 0; d < 4; d++) {
                    ah.u[d] = PERM_HI(w_[2 * d + 1], w_[2 * d]);
                    al.u[d] = PERM_LO(w_[2 * d + 1], w_[2 * d]);
                }
                short8 bh = pb[s * 64];
                short8 bl = pb[(9 + s) * 64];
                acc = MFMA(ah.v, bh, acc);
                acc = MFMA(ah.v, bl, acc);
                acc = MFMA(al.v, bh, acc);
            }
            #pragma unroll
            for (int r5 = 0; r5 < 16; r5++) {
                int row = (r5 & 3) + 8 * (r5 >> 2) + 4 * hf;
                int pxw = mt * 32 + row;
                if (pxw < 196) {
                    float y = fmaxf(fmaf(acc[r5], sc, sh), 0.f);
                    h2g[(long)b * 6272 + pxw * 32 + mloc] = splitpack(y);
                }
            }
        }
    }
}

// ---- conv3 + conv4 MFMA GEMMs + BN/ReLU/pool/xin + sensory; 2 images/block ----
// LDS: h2s 2x6501 u32 (px stride 33, odd -> conflict-free) + h3s 2x3250 (stride 65)
// = 78008 B -> 2 blocks/CU x 8 waves = 16 waves/CU. B-weights read once per 2 images.
__global__ __launch_bounds__(512, 4) void k_conv34s(
    const unsigned* __restrict__ h2g, const float* __restrict__ b3g,
    const float* __restrict__ inw, const float* __restrict__ inb,
    const float* __restrict__ smu, const float* __restrict__ ssig,
    const float* __restrict__ ws,
    float* __restrict__ wn, float* __restrict__ wd, int nimg) {
    __shared__ unsigned h2s[13002];  // [img2][px196 + zero-row][stride 33]; reused as xin later
    __shared__ unsigned h3s[6500];   // [img2][px49 + zero-row][stride 65]
    const float* par = ws + OFF_PAR;
    int b = blockIdx.x, tid = threadIdx.x;
    int g0 = b * 2;
    int g1 = (g0 + 1 < nimg) ? g0 + 1 : g0;
    {
        const unsigned* s0 = h2g + (long)g0 * 6272;
        const unsigned* s1 = h2g + (long)g1 * 6272;
        for (int i = tid; i < 12544; i += 512) {
            int img = i >> 12 >> 1;              // i/8192? no: use explicit
            img = i / 6272;
            int r = i - img * 6272;
            int px = r >> 5, ci = r & 31;
            h2s[img * 6501 + px * 33 + ci] = (img ? s1 : s0)[r];
        }
        if (tid < 66) h2s[(tid >> 5 >> 0 < 1 ? 0 : 0)] = h2s[0];  // placeholder no-op
        // zero rows (px=196 in each image)
        if (tid < 33) h2s[196 * 33 + tid] = 0u;
        else if (tid < 66) h2s[6501 + 196 * 33 + (tid - 33)] = 0u;
        if (tid < 65) h3s[49 * 65 + tid] = 0u;
        else if (tid < 130) h3s[3250 + 49 * 65 + (tid - 65)] = 0u;
    }
    __syncthreads();
    int wv = tid >> 6;
    int lane = tid & 63;
    int mloc = lane & 31, hf = lane >> 5, half8 = hf * 8;

    // ---- conv3 GEMM: per image C[64px(49) x 64co], K=800 (k = tap*32 + ci) ----
    {
        int img = wv >> 2, mt = wv & 1, nt = (wv >> 1) & 1;
        int imgo2 = img * 6501;
        int px = mt * 32 + mloc;
        int oh = px / 7, ow = px % 7;
        bool pxok = px < 49;
        int oh2 = oh * 2 - 2, ow2 = ow * 2 - 2;
        int co3 = nt * 32 + mloc;
        float bias = b3g[co3];
        f32x16 acc;
        #pragma unroll
        for (int i = 0; i < 16; i++) acc[i] = bias;
        const u16_t* B3 = (const u16_t*)(ws + OFF_B3F);
        const short8* pbh = (const short8*)(B3 + (long)(nt * 50) * 512) + lane;
        const short8* pbl = (const short8*)(B3 + (long)((2 + nt) * 50) * 512) + lane;
        int s = 0;
        for (int kh = 0; kh < 5; kh++) {
            int ih = oh2 + kh;
            #pragma unroll
            for (int kw = 0; kw < 5; kw++) {
                int iw = ow2 + kw;
                bool ok = pxok && ((unsigned)ih < 14u) && ((unsigned)iw < 14u);
                int rowb = imgo2 + (ok ? (ih * 14 + iw) : 196) * 33;
                #pragma unroll
                for (int sub = 0; sub < 2; sub++) {
                    const unsigned* ap = h2s + rowb + sub * 16 + half8;
                    unsigned w_[8];
                    #pragma unroll
                    for (int j = 0; j < 8; j++) w_[j] = ap[j];
                    U8 ah, al;
                    #pragma unroll
                    for (int d = 0; d < 4; d++) {
                        ah.u[d] = PERM_HI(w_[2 * d + 1], w_[2 * d]);
                        al.u[d] = PERM_LO(w_[2 * d + 1], w_[2 * d]);
                    }
                    short8 bh = pbh[s * 64];
                    short8 bl = pbl[s * 64];
                    acc = MFMA(ah.v, bh, acc);
                    acc = MFMA(ah.v, bl, acc);
                    acc = MFMA(al.v, bh, acc);
                    s++;
                }
            }
        }
        // epilogue: ReLU, split, write h3 packed [img][px][co]
        #pragma unroll
        for (int r5 = 0; r5 < 16; r5++) {
            int row = (r5 & 3) + 8 * (r5 >> 2) + 4 * hf;
            int pxw = mt * 32 + row;
            if (pxw < 49) {
                float y = fmaxf(acc[r5], 0.f);
                h3s[img * 3250 + pxw * 65 + co3] = splitpack(y);
            }
        }
    }
    __syncthreads();
    // ---- conv4 GEMM: per image C[32px(16) x 128co], K=1600 (k = tap*64 + ci) ----
    {
        int img = wv >> 2, nt = wv & 3;
        int imgo3 = img * 3250;
        int oh = mloc >> 2, ow = mloc & 3;
        bool pxok = mloc < 16;
        int oh2 = oh * 2 - 2, ow2 = ow * 2 - 2;
        int co4 = nt * 32 + mloc;
        f32x16 acc;
        #pragma unroll
        for (int i = 0; i < 16; i++) acc[i] = 0.f;
        const u16_t* B4 = (const u16_t*)(ws + OFF_B4F);
        const short8* pbh = (const short8*)(B4 + (long)(nt * 100) * 512) + lane;
        const short8* pbl = (const short8*)(B4 + (long)((4 + nt) * 100) * 512) + lane;
        int s = 0;
        for (int kh = 0; kh < 5; kh++) {
            int ih = oh2 + kh;
            #pragma unroll
            for (int kw = 0; kw < 5; kw++) {
                int iw = ow2 + kw;
                bool ok = pxok && ((unsigned)ih < 7u) && ((unsigned)iw < 7u);
                int rowb = imgo3 + (ok ? (ih * 7 + iw) : 49) * 65;
                #pragma unroll
                for (int sub = 0; sub < 4; sub++) {
                    const unsigned* ap = h3s + rowb + sub * 16 + half8;
                    unsigned w_[8];
                    #pragma unroll
                    for (int j = 0; j < 8; j++) w_[j] = ap[j];
                    U8 ah, al;
                    #pragma unroll
                    for (int d = 0; d < 4; d++) {
                        ah.u[d] = PERM_HI(w_[2 * d + 1], w_[2 * d]);
                        al.u[d] = PERM_LO(w_[2 * d + 1], w_[2 * d]);
                    }
                    short8 bh = pbh[s * 64];
                    short8 bl = pbl[s * 64];
                    acc = MFMA(ah.v, bh, acc);
                    acc = MFMA(ah.v, bl, acc);
                    acc = MFMA(al.v, bh, acc);
                    s++;
                }
            }
        }
        // epilogue: BN+ReLU (regs 0..7 = px 0..15), shfl 2x2 maxpool, xin
        float sc = par[P_SC4 + co4], sh = par[P_SH4 + co4];
        float y[8];
        #pragma unroll
        for (int p = 0; p < 8; p++) y[p] = fmaxf(fmaf(acc[p], sc, sh), 0.f);
        __syncthreads();   // h2s dead; reuse as xin[img2][32][16] f32
        float* xin_s = (float*)h2s;
        #pragma unroll
        for (int q = 0; q < 4; q++) {
            int ph = q >> 1, pw = q & 1;
            int r1 = ph * 4 + pw * 2;
            float part = fmaxf(y[r1], y[r1 + 1]);
            part = fmaxf(part, __shfl_xor(part, 32));
            if (lane < 32) {
                int f = ((co4 & 3) << 2) + q;
                xin_s[img * 512 + (co4 >> 2) * 16 + f] = fmaf(part, inw[f], inb[f]);
            }
        }
    }
    __syncthreads();
    // ---- sensory synapses: wnum/wden per image [32 t][19 n] ----
    const float* xin_s = (const float*)h2s;
    for (int idx = tid; idx < 1216; idx += 512) {
        int img = idx / 608;
        int r = idx - img * 608;
        int tt = r / 19, n = r - tt * 19;
        int gi = g0 + img;
        if (gi >= nimg) break;
        float nu = 0.f, de = 0.f;
        #pragma unroll
        for (int s = 0; s < 16; s++) {
            float sg = sigmoidf_((xin_s[img * 512 + tt * 16 + s] - smu[s * 19 + n]) * ssig[s * 19 + n]);
            nu = fmaf(par[P_SWME + s * 19 + n], sg, nu);
            de = fmaf(par[P_SWM + s * 19 + n], sg, de);
        }
        wn[((long)gi * 32 + tt) * 19 + n] = nu;
        wd[((long)gi * 32 + tt) * 19 + n] = de;
    }
}

// ---------------- LTC recurrence: 3 images x 19 neurons per wave ----------------
// __launch_bounds__(256,2): VGPR cap 256 so the 4x19 param arrays stay register-
// resident (default heuristic capped at 60 VGPR -> per-unfold scratch reloads).
__global__ __launch_bounds__(256, 2) void k_ltc(
    const float* __restrict__ mu_g, const float* __restrict__ sg_g,
    const float* __restrict__ ws,
    const float* __restrict__ wn, const float* __restrict__ wd,
    const float* __restrict__ outw, const float* __restrict__ outb,
    float* __restrict__ out, int img0, int nimg) {
    const float* par = ws + OFF_PAR;
    int tid = threadIdx.x, wave = tid >> 6, lane = tid & 63;
    int li = lane / 19, j = lane - li * 19;
    if (li > 2) { li = 2; j = 18; }
    int il = blockIdx.x * 12 + wave * 3 + li;
    int ilc = il < nimg ? il : nimg - 1;

    const float L2E = 1.44269504f;
    // sigmoid((v-mu)*sig) = rcp(1 + exp2(v*a + b)), a = -sig*log2e, b = mu*sig*log2e
    float aj[19], bj[19], wpj[19], wpej[19];
    #pragma unroll
    for (int i = 0; i < 19; i++) {
        float mu = mu_g[i * 19 + j];
        float sg = sg_g[i * 19 + j];
        aj[i] = -sg * L2E;
        bj[i] = mu * sg * L2E;
        wpj[i] = par[P_WP + i * 19 + j];
        wpej[i] = par[P_WPE + i * 19 + j];
    }
    float cmt = par[P_CMT + j], gl = par[P_GL + j], glvl = par[P_GLVL + j];
    float v = 0.f;
    long base0 = (long)ilc * 608 + j;
    float wns = wn[base0], wds = wd[base0];
    for (int t = 0; t < 32; t++) {
        float wns_n = 0.f, wds_n = 0.f;
        if (t < 31) {
            long basen = base0 + (t + 1) * 19;
            wns_n = wn[basen];
            wds_n = wd[basen];
        }
        #pragma unroll 1
        for (int u = 0; u < 6; u++) {
            float n0 = 0.f, n1 = 0.f, d0 = 0.f, d1 = 0.f;
            #pragma unroll
            for (int i = 0; i < 19; i++) {
                float vi = __shfl(v, li * 19 + i, 64);
                float e = __builtin_amdgcn_exp2f(fmaf(vi, aj[i], bj[i]));
                float s = __builtin_amdgcn_rcpf(1.0f + e);
                if (i & 1) { n1 = fmaf(wpej[i], s, n1); d1 = fmaf(wpj[i], s, d1); }
                else       { n0 = fmaf(wpej[i], s, n0); d0 = fmaf(wpj[i], s, d0); }
            }
            float num = fmaf(cmt, v, glvl) + wns + (n0 + n1);
            float den = cmt + gl + wds + (d0 + d1);
            v = num * __builtin_amdgcn_rcpf(den + 1e-8f);
        }
        wns = wns_n; wds = wds_n;
    }
    if (j < 2 && il < nimg && lane < 57)
        out[(long)(img0 + il) * 2 + j] = fmaf(v, outw[j], outb[j]);
}

extern "C" void kernel_launch(void* const* d_in, const int* in_sizes, int n_in,
                              void* d_out, int out_size, void* d_ws, size_t ws_size,
                              hipStream_t stream) {
    const float* x    = (const float*)d_in[0];
    const float* w1   = (const float*)d_in[1];
    const float* b1   = (const float*)d_in[2];
    const float* w2   = (const float*)d_in[3];
    const float* b2   = (const float*)d_in[4];
    const float* g2   = (const float*)d_in[5];
    const float* be2  = (const float*)d_in[6];
    const float* m2   = (const float*)d_in[7];
    const float* v2   = (const float*)d_in[8];
    const float* w3   = (const float*)d_in[9];
    const float* b3   = (const float*)d_in[10];
    const float* w4   = (const float*)d_in[11];
    const float* b4   = (const float*)d_in[12];
    const float* g4   = (const float*)d_in[13];
    const float* be4  = (const float*)d_in[14];
    const float* m4   = (const float*)d_in[15];
    const float* v4   = (const float*)d_in[16];
    const float* inw  = (const float*)d_in[17];
    const float* inb  = (const float*)d_in[18];
    const float* smu  = (const float*)d_in[19];
    const float* ssig = (const float*)d_in[20];
    const float* sw   = (const float*)d_in[21];
    const float* serv = (const float*)d_in[22];
    const float* smk  = (const float*)d_in[23];
    const float* mu_  = (const float*)d_in[24];
    const float* sig_ = (const float*)d_in[25];
    const float* w_   = (const float*)d_in[26];
    const float* erev = (const float*)d_in[27];
    const float* mask = (const float*)d_in[28];
    const float* glk  = (const float*)d_in[29];
    const float* vlk  = (const float*)d_in[30];
    const float* cm   = (const float*)d_in[31];
    const float* outw = (const float*)d_in[32];
    const float* outb = (const float*)d_in[33];
    float* ws = (float*)d_ws;

    k_prep<<<64, 256, 0, stream>>>(w2, w3, w4, sw, serv, smk, w_, erev, mask,
                                   glk, vlk, cm, b2, g2, be2, m2, v2,
                                   b4, g4, be4, m4, v4, ws);

    // auto-size batch chunk: per-image = h2(6272 u32) + wn/wd(1216 f32)
    long avail = (long)(ws_size / 4) - OFF_DYN;
    long per = 6272 + 1216;
    int chunk = (int)(avail / per);
    if (chunk > BATCH) chunk = BATCH;
    if (chunk < 2) chunk = 2;
    if (chunk > BATCH) chunk = BATCH;

    float* wnp = ws + OFF_DYN;
    float* wdp = wnp + (long)chunk * 608;
    unsigned* h2 = (unsigned*)(wdp + (long)chunk * 608);

    for (int c0 = 0; c0 < BATCH; c0 += chunk) {
        int n = (BATCH - c0 < chunk) ? (BATCH - c0) : chunk;
        k_conv12<<<n, 512, 0, stream>>>(x + (long)c0 * 784, w1, b1, ws, h2);
        k_conv34s<<<(n + 1) / 2, 512, 0, stream>>>(h2, b3, inw, inb, smu, ssig, ws,
                                                   wnp, wdp, n);
        k_ltc<<<(n + 11) / 12, 256, 0, stream>>>(mu_, sig_, ws, wnp, wdp, outw, outb,
                                                 (float*)d_out, c0, n);
    }
}